// Round 1
// baseline (3706.852 us; speedup 1.0000x reference)
//
#include <hip/hip_runtime.h>
#include <hip/hip_bf16.h>

#define S_ 1024
#define H_ 2048
#define NH_ 32
#define NKV_ 4
#define HD_ 128
#define NE_ 32
#define TOPK_ 8
#define I_ 768
#define EPS_ 1e-6f

typedef __bf16 bf16_t;
typedef __bf16 bf16x8 __attribute__((ext_vector_type(8)));
typedef float f32x4 __attribute__((ext_vector_type(4)));

#define BM 128
#define BN 128
#define BK 32
#define LDK 40   // BK + 8 pad: 80B row stride, 16B-aligned

// ---------------- RMSNorm over H (one block per row) ----------------
__global__ __launch_bounds__(256) void rmsnorm_k(const float* __restrict__ x,
                                                 const float* __restrict__ w,
                                                 float* __restrict__ out) {
  int r = blockIdx.x, tid = threadIdx.x;
  const float* xr = x + (size_t)r * H_;
  f32x4 a = *(const f32x4*)(xr + tid * 8);
  f32x4 b = *(const f32x4*)(xr + tid * 8 + 4);
  float ss = 0.f;
#pragma unroll
  for (int i = 0; i < 4; ++i) ss += a[i] * a[i] + b[i] * b[i];
#pragma unroll
  for (int m = 1; m < 64; m <<= 1) ss += __shfl_xor(ss, m);
  __shared__ float wsum[4];
  if ((tid & 63) == 0) wsum[tid >> 6] = ss;
  __syncthreads();
  ss = wsum[0] + wsum[1] + wsum[2] + wsum[3];
  float inv = rsqrtf(ss * (1.0f / H_) + EPS_);
  f32x4 w0 = *(const f32x4*)(w + tid * 8);
  f32x4 w1 = *(const f32x4*)(w + tid * 8 + 4);
  f32x4 o0, o1;
#pragma unroll
  for (int i = 0; i < 4; ++i) { o0[i] = a[i] * inv * w0[i]; o1[i] = b[i] * inv * w1[i]; }
  *(f32x4*)(out + (size_t)r * H_ + tid * 8) = o0;
  *(f32x4*)(out + (size_t)r * H_ + tid * 8 + 4) = o1;
}

// ---------------- generic bf16-MFMA GEMM, 128x128x32 tiles ----------------
// C[M,N] = A[M,K] @ B[K,N]  (+resid) (*per-row scale)   fp32 in (or bf16), out TC
template <typename TA, typename TC, bool EXPERT, bool RESID, bool SCALE>
__global__ __launch_bounds__(256, 2) void gemm_k(
    const TA* __restrict__ A, const float* __restrict__ B,
    const float* __restrict__ resid, TC* __restrict__ C,
    const float* __restrict__ wlist, const int* __restrict__ counts,
    const int* __restrict__ offsets, int M, int N, int K) {
  int cnt = M;
  const TA* Ab = A;
  const float* Bb = B;
  TC* Cb = C;
  const float* wl = nullptr;
  if constexpr (EXPERT) {
    int e = blockIdx.z;
    cnt = counts[e];
    if ((int)(blockIdx.x * BM) >= cnt) return;
    int off = offsets[e];
    Ab = A + (size_t)off * K;
    Cb = C + (size_t)off * N;
    Bb = B + (size_t)e * K * N;
    if constexpr (SCALE) wl = wlist + (size_t)e * S_;
  }
  __shared__ bf16_t As[BM][LDK];
  __shared__ bf16_t Bs[BN][LDK];   // transposed: Bs[n][k]
  int tid = threadIdx.x;
  int lane = tid & 63, wid = tid >> 6;
  int wr = (wid >> 1) * 64, wc = (wid & 1) * 64;
  int fr = lane & 15, kg = (lane >> 4) * 8;
  int m0 = blockIdx.x * BM, n0 = blockIdx.y * BN;

  int sar = tid >> 1, sac = (tid & 1) * 16;          // A stage: 2 thr/row, 16 cols each
  int gar = min(m0 + sar, cnt - 1);
  const TA* aptr = Ab + (size_t)gar * K + sac;
  int sbr = tid >> 3, sbc = (tid & 7) * 16;          // B stage: 8 thr/row, 16 cols each
  const float* bptr = Bb + (size_t)sbr * N + n0 + sbc;

  f32x4 acc[4][4] = {};

  for (int k0 = 0; k0 < K; k0 += BK) {
    // stage A (convert fp32->bf16 if needed)
    bf16x8 av0, av1;
    if constexpr (sizeof(TA) == 4) {
      f32x4 t0 = *(const f32x4*)(aptr + k0);
      f32x4 t1 = *(const f32x4*)(aptr + k0 + 4);
      f32x4 t2 = *(const f32x4*)(aptr + k0 + 8);
      f32x4 t3 = *(const f32x4*)(aptr + k0 + 12);
#pragma unroll
      for (int i = 0; i < 4; ++i) {
        av0[i] = (__bf16)t0[i]; av0[i + 4] = (__bf16)t1[i];
        av1[i] = (__bf16)t2[i]; av1[i + 4] = (__bf16)t3[i];
      }
    } else {
      av0 = *(const bf16x8*)(aptr + k0);
      av1 = *(const bf16x8*)(aptr + k0 + 8);
    }
    *(bf16x8*)&As[sar][sac] = av0;
    *(bf16x8*)&As[sar][sac + 8] = av1;
    // stage B transposed
    {
      const float* bp = bptr + (size_t)k0 * N;
      f32x4 b0 = *(const f32x4*)(bp);
      f32x4 b1 = *(const f32x4*)(bp + 4);
      f32x4 b2 = *(const f32x4*)(bp + 8);
      f32x4 b3 = *(const f32x4*)(bp + 12);
#pragma unroll
      for (int i = 0; i < 4; ++i) {
        Bs[sbc + i][sbr]      = (bf16_t)b0[i];
        Bs[sbc + 4 + i][sbr]  = (bf16_t)b1[i];
        Bs[sbc + 8 + i][sbr]  = (bf16_t)b2[i];
        Bs[sbc + 12 + i][sbr] = (bf16_t)b3[i];
      }
    }
    __syncthreads();
    bf16x8 af[4], bfv[4];
#pragma unroll
    for (int i = 0; i < 4; ++i) af[i] = *(const bf16x8*)&As[wr + i * 16 + fr][kg];
#pragma unroll
    for (int i = 0; i < 4; ++i) bfv[i] = *(const bf16x8*)&Bs[wc + i * 16 + fr][kg];
#pragma unroll
    for (int mi = 0; mi < 4; ++mi)
#pragma unroll
      for (int ni = 0; ni < 4; ++ni)
        acc[mi][ni] = __builtin_amdgcn_mfma_f32_16x16x32_bf16(af[mi], bfv[ni], acc[mi][ni], 0, 0, 0);
    __syncthreads();
  }
  int rbase = (lane >> 4) * 4;
#pragma unroll
  for (int mi = 0; mi < 4; ++mi)
#pragma unroll
    for (int ni = 0; ni < 4; ++ni)
#pragma unroll
      for (int r = 0; r < 4; ++r) {
        int lr = wr + mi * 16 + rbase + r;
        int gi = m0 + lr;
        if (EXPERT && gi >= cnt) continue;
        int gc = n0 + wc + ni * 16 + fr;
        float v = acc[mi][ni][r];
        if constexpr (SCALE) v *= wl[gi];
        if constexpr (RESID) v += resid[(size_t)gi * N + gc];
        Cb[(size_t)gi * N + gc] = (TC)v;
      }
}

// ---------------- Q/K head-RMSNorm + RoPE (in place) ----------------
__global__ __launch_bounds__(64) void qknorm_rope_k(float* __restrict__ qb, float* __restrict__ kb,
                                                    const float* __restrict__ qn,
                                                    const float* __restrict__ kn,
                                                    const float* __restrict__ pe) {
  int s = blockIdx.x, hh = blockIdx.y, lane = threadIdx.x;
  float* ptr;
  const float* w;
  if (hh < NH_) { ptr = qb + (size_t)s * NH_ * HD_ + hh * HD_; w = qn; }
  else          { ptr = kb + (size_t)s * NKV_ * HD_ + (hh - NH_) * HD_; w = kn; }
  float x0 = ptr[2 * lane], x1 = ptr[2 * lane + 1];
  float ss = x0 * x0 + x1 * x1;
#pragma unroll
  for (int m = 1; m < 64; m <<= 1) ss += __shfl_xor(ss, m);
  float inv = rsqrtf(ss * (1.0f / HD_) + EPS_);
  x0 = x0 * inv * w[2 * lane];
  x1 = x1 * inv * w[2 * lane + 1];
  float ang = pe[(size_t)s * (HD_ / 2) + lane];
  float sn, cs;
  sincosf(ang, &sn, &cs);
  ptr[2 * lane] = x0 * cs - x1 * sn;
  ptr[2 * lane + 1] = x0 * sn + x1 * cs;
}

// ---------------- causal GQA attention, 1 wave per (row, head) ----------------
__global__ __launch_bounds__(64) void attn_k(const float* __restrict__ q,
                                             const float* __restrict__ k,
                                             const float* __restrict__ v,
                                             float* __restrict__ o) {
  int s = blockIdx.x, h = blockIdx.y, lane = threadIdx.x;
  int kvh = h >> 3;
  __shared__ __align__(16) float qs[HD_];
  __shared__ float p[S_];
  const float* qrow = q + (size_t)s * (NH_ * HD_) + h * HD_;
  qs[lane] = qrow[lane];
  qs[lane + 64] = qrow[lane + 64];
  __syncthreads();
  const float scale = 0.08838834764831845f;  // 1/sqrt(128)
  float lmax = -3.0e38f;
  for (int j = lane; j <= s; j += 64) {
    const f32x4* kr = (const f32x4*)(k + ((size_t)j * NKV_ + kvh) * HD_);
    const f32x4* q4 = (const f32x4*)qs;
    float acc = 0.f;
#pragma unroll 8
    for (int d = 0; d < HD_ / 4; ++d) {
      f32x4 kv = kr[d], qv = q4[d];
      acc += kv[0] * qv[0] + kv[1] * qv[1] + kv[2] * qv[2] + kv[3] * qv[3];
    }
    float sc = acc * scale;
    p[j] = sc;
    lmax = fmaxf(lmax, sc);
  }
#pragma unroll
  for (int m = 1; m < 64; m <<= 1) lmax = fmaxf(lmax, __shfl_xor(lmax, m));
  __syncthreads();
  float sum = 0.f;
  for (int j = lane; j <= s; j += 64) {
    float e = __expf(p[j] - lmax);
    p[j] = e;
    sum += e;
  }
#pragma unroll
  for (int m = 1; m < 64; m <<= 1) sum += __shfl_xor(sum, m);
  __syncthreads();
  float o0 = 0.f, o1 = 0.f;
  int d0 = lane * 2;
#pragma unroll 4
  for (int j = 0; j <= s; ++j) {
    float wj = p[j];
    const float* vr = v + ((size_t)j * NKV_ + kvh) * HD_;
    o0 += wj * vr[d0];
    o1 += wj * vr[d0 + 1];
  }
  float invs = 1.0f / sum;
  float* orow = o + (size_t)s * (NH_ * HD_) + h * HD_;
  orow[d0] = o0 * invs;
  orow[d0 + 1] = o1 * invs;
}

// ---------------- router: logits, softmax-free top-8, renorm, expert lists ----------------
__global__ __launch_bounds__(256) void router_k(const float* __restrict__ h2,
                                                const float* __restrict__ gw,
                                                int* __restrict__ counts, int* __restrict__ toklist,
                                                float* __restrict__ wlist, int* __restrict__ sel,
                                                int* __restrict__ pos) {
  int t = blockIdx.x, tid = threadIdx.x;
  int e = tid & 31, grp = tid >> 5;
  float acc = 0.f;
  for (int kk = grp; kk < H_; kk += 8)
    acc += h2[(size_t)t * H_ + kk] * gw[(size_t)kk * NE_ + e];
  __shared__ float part[8][32];
  part[grp][e] = acc;
  __syncthreads();
  if (tid == 0) {
    float lg[NE_];
    for (int ee = 0; ee < NE_; ++ee) {
      float s = 0.f;
      for (int g = 0; g < 8; ++g) s += part[g][ee];
      lg[ee] = s;
    }
    float m = lg[0];
    for (int ee = 1; ee < NE_; ++ee) m = fmaxf(m, lg[ee]);
    // softmax numerators only: renormalization cancels the denominator
    for (int ee = 0; ee < NE_; ++ee) lg[ee] = __expf(lg[ee] - m);
    bool used[NE_] = {};
    float rw[TOPK_]; int se[TOPK_]; float tot = 0.f;
    for (int kk = 0; kk < TOPK_; ++kk) {
      float best = -1.f; int bi = 0;
      for (int ee = 0; ee < NE_; ++ee)
        if (!used[ee] && lg[ee] > best) { best = lg[ee]; bi = ee; }
      used[bi] = true; se[kk] = bi; rw[kk] = best; tot += best;
    }
    float itot = 1.0f / tot;
    for (int kk = 0; kk < TOPK_; ++kk) {
      int ee = se[kk];
      int pp = atomicAdd(&counts[ee], 1);
      toklist[ee * S_ + pp] = t;
      wlist[ee * S_ + pp] = rw[kk] * itot;
      sel[t * TOPK_ + kk] = ee;
      pos[t * TOPK_ + kk] = pp;
    }
  }
}

__global__ void scan_k(const int* __restrict__ counts, int* __restrict__ offsets) {
  if (threadIdx.x == 0 && blockIdx.x == 0) {
    int o = 0;
    for (int e = 0; e < NE_; ++e) { offsets[e] = o; o += counts[e]; }
    offsets[NE_] = o;
  }
}

// ---------------- MoE up: ACT[slot,i] = silu(h2@wg) * (h2@wu), bf16 out ----------------
__global__ __launch_bounds__(256, 1) void moe_up_k(const float* __restrict__ h2,
                                                   const float* __restrict__ wg,
                                                   const float* __restrict__ wu,
                                                   const int* __restrict__ toklist,
                                                   const int* __restrict__ counts,
                                                   const int* __restrict__ offsets,
                                                   bf16_t* __restrict__ act) {
  int eidx = blockIdx.z;
  int cnt = counts[eidx];
  int m0 = blockIdx.x * BM;
  if (m0 >= cnt) return;
  int n0 = blockIdx.y * BN;
  const int* toks = toklist + (size_t)eidx * S_;
  const float* Bg = wg + (size_t)eidx * H_ * I_;
  const float* Bu = wu + (size_t)eidx * H_ * I_;
  __shared__ bf16_t As[BM][LDK];
  __shared__ bf16_t Gs[BN][LDK];
  __shared__ bf16_t Us[BN][LDK];
  int tid = threadIdx.x, lane = tid & 63, wid = tid >> 6;
  int wr = (wid >> 1) * 64, wc = (wid & 1) * 64;
  int fr = lane & 15, kg = (lane >> 4) * 8;
  int sar = tid >> 1, sac = (tid & 1) * 16;
  int gi_l = min(m0 + sar, cnt - 1);
  const float* aptr = h2 + (size_t)toks[gi_l] * H_ + sac;
  int sbr = tid >> 3, sbc = (tid & 7) * 16;
  const float* gptr = Bg + (size_t)sbr * I_ + n0 + sbc;
  const float* uptr = Bu + (size_t)sbr * I_ + n0 + sbc;
  f32x4 accg[4][4] = {}, accu[4][4] = {};
  for (int k0 = 0; k0 < H_; k0 += BK) {
    {
      f32x4 t0 = *(const f32x4*)(aptr + k0);
      f32x4 t1 = *(const f32x4*)(aptr + k0 + 4);
      f32x4 t2 = *(const f32x4*)(aptr + k0 + 8);
      f32x4 t3 = *(const f32x4*)(aptr + k0 + 12);
      bf16x8 av0, av1;
#pragma unroll
      for (int i = 0; i < 4; ++i) {
        av0[i] = (__bf16)t0[i]; av0[i + 4] = (__bf16)t1[i];
        av1[i] = (__bf16)t2[i]; av1[i + 4] = (__bf16)t3[i];
      }
      *(bf16x8*)&As[sar][sac] = av0;
      *(bf16x8*)&As[sar][sac + 8] = av1;
    }
    {
      const float* bp = gptr + (size_t)k0 * I_;
      f32x4 b0 = *(const f32x4*)(bp);
      f32x4 b1 = *(const f32x4*)(bp + 4);
      f32x4 b2 = *(const f32x4*)(bp + 8);
      f32x4 b3 = *(const f32x4*)(bp + 12);
#pragma unroll
      for (int i = 0; i < 4; ++i) {
        Gs[sbc + i][sbr]      = (bf16_t)b0[i];
        Gs[sbc + 4 + i][sbr]  = (bf16_t)b1[i];
        Gs[sbc + 8 + i][sbr]  = (bf16_t)b2[i];
        Gs[sbc + 12 + i][sbr] = (bf16_t)b3[i];
      }
    }
    {
      const float* bp = uptr + (size_t)k0 * I_;
      f32x4 b0 = *(const f32x4*)(bp);
      f32x4 b1 = *(const f32x4*)(bp + 4);
      f32x4 b2 = *(const f32x4*)(bp + 8);
      f32x4 b3 = *(const f32x4*)(bp + 12);
#pragma unroll
      for (int i = 0; i < 4; ++i) {
        Us[sbc + i][sbr]      = (bf16_t)b0[i];
        Us[sbc + 4 + i][sbr]  = (bf16_t)b1[i];
        Us[sbc + 8 + i][sbr]  = (bf16_t)b2[i];
        Us[sbc + 12 + i][sbr] = (bf16_t)b3[i];
      }
    }
    __syncthreads();
    bf16x8 af[4], gf[4], uf[4];
#pragma unroll
    for (int i = 0; i < 4; ++i) af[i] = *(const bf16x8*)&As[wr + i * 16 + fr][kg];
#pragma unroll
    for (int i = 0; i < 4; ++i) gf[i] = *(const bf16x8*)&Gs[wc + i * 16 + fr][kg];
#pragma unroll
    for (int i = 0; i < 4; ++i) uf[i] = *(const bf16x8*)&Us[wc + i * 16 + fr][kg];
#pragma unroll
    for (int mi = 0; mi < 4; ++mi)
#pragma unroll
      for (int ni = 0; ni < 4; ++ni) {
        accg[mi][ni] = __builtin_amdgcn_mfma_f32_16x16x32_bf16(af[mi], gf[ni], accg[mi][ni], 0, 0, 0);
        accu[mi][ni] = __builtin_amdgcn_mfma_f32_16x16x32_bf16(af[mi], uf[ni], accu[mi][ni], 0, 0, 0);
      }
    __syncthreads();
  }
  int rbase = (lane >> 4) * 4;
  int slotbase = offsets[eidx];
#pragma unroll
  for (int mi = 0; mi < 4; ++mi)
#pragma unroll
    for (int ni = 0; ni < 4; ++ni)
#pragma unroll
      for (int r = 0; r < 4; ++r) {
        int lr = wr + mi * 16 + rbase + r;
        int gi = m0 + lr;
        if (gi < cnt) {
          float g = accg[mi][ni][r], u = accu[mi][ni][r];
          float sig = 1.0f / (1.0f + __expf(-g));
          float a = g * sig * u;
          act[(size_t)(slotbase + gi) * I_ + n0 + wc + ni * 16 + fr] = (bf16_t)a;
        }
      }
}

// ---------------- combine: out = x1 + sum over the token's 8 expert slots ----------------
__global__ __launch_bounds__(256) void combine_k(const float* __restrict__ x1,
                                                 const bf16_t* __restrict__ pairout,
                                                 const int* __restrict__ sel,
                                                 const int* __restrict__ pos,
                                                 const int* __restrict__ offsets,
                                                 float* __restrict__ out) {
  int t = blockIdx.x, tid = threadIdx.x;
  int slots[TOPK_];
#pragma unroll
  for (int kk = 0; kk < TOPK_; ++kk)
    slots[kk] = offsets[sel[t * TOPK_ + kk]] + pos[t * TOPK_ + kk];
  int c = tid * 8;
  f32x4 s0 = *(const f32x4*)(x1 + (size_t)t * H_ + c);
  f32x4 s1 = *(const f32x4*)(x1 + (size_t)t * H_ + c + 4);
#pragma unroll
  for (int kk = 0; kk < TOPK_; ++kk) {
    bf16x8 pv = *(const bf16x8*)(pairout + (size_t)slots[kk] * H_ + c);
#pragma unroll
    for (int i = 0; i < 4; ++i) { s0[i] += (float)pv[i]; s1[i] += (float)pv[i + 4]; }
  }
  *(f32x4*)(out + (size_t)t * H_ + c) = s0;
  *(f32x4*)(out + (size_t)t * H_ + c + 4) = s1;
}

extern "C" void kernel_launch(void* const* d_in, const int* in_sizes, int n_in,
                              void* d_out, int out_size, void* d_ws, size_t ws_size,
                              hipStream_t stream) {
  const float* hidden = (const float*)d_in[0];
  const float* pe     = (const float*)d_in[1];
  // d_in[2] attention_mask: pure causal, applied analytically. d_in[3] start_pos: 0, unused.
  const float* ln1    = (const float*)d_in[4];
  const float* ln2    = (const float*)d_in[5];
  const float* q_w    = (const float*)d_in[6];
  const float* k_w    = (const float*)d_in[7];
  const float* v_w    = (const float*)d_in[8];
  const float* o_w    = (const float*)d_in[9];
  const float* qn     = (const float*)d_in[10];
  const float* kn     = (const float*)d_in[11];
  const float* gate_w = (const float*)d_in[12];
  const float* wg     = (const float*)d_in[13];
  const float* wu     = (const float*)d_in[14];
  const float* wd     = (const float*)d_in[15];
  float* out = (float*)d_out;

  char* p = (char*)d_ws;
  auto alloc = [&](size_t bytes) {
    char* r = p;
    p += (bytes + 255) & ~(size_t)255;
    return r;
  };
  float*  h1      = (float*)alloc((size_t)S_ * H_ * 4);
  float*  qb      = (float*)alloc((size_t)S_ * NH_ * HD_ * 4);
  float*  kb      = (float*)alloc((size_t)S_ * NKV_ * HD_ * 4);
  float*  vb      = (float*)alloc((size_t)S_ * NKV_ * HD_ * 4);
  float*  ao      = (float*)alloc((size_t)S_ * NH_ * HD_ * 4);
  float*  x1      = (float*)alloc((size_t)S_ * H_ * 4);
  float*  h2      = (float*)alloc((size_t)S_ * H_ * 4);
  bf16_t* act     = (bf16_t*)alloc((size_t)S_ * TOPK_ * I_ * 2);
  bf16_t* po      = (bf16_t*)alloc((size_t)S_ * TOPK_ * H_ * 2);
  int*    counts  = (int*)alloc(NE_ * 4);
  int*    offs    = (int*)alloc((NE_ + 1) * 4);
  int*    toklist = (int*)alloc((size_t)NE_ * S_ * 4);
  float*  wlist   = (float*)alloc((size_t)NE_ * S_ * 4);
  int*    sel     = (int*)alloc((size_t)S_ * TOPK_ * 4);
  int*    pos     = (int*)alloc((size_t)S_ * TOPK_ * 4);

  hipMemsetAsync(counts, 0, NE_ * 4, stream);

  rmsnorm_k<<<S_, 256, 0, stream>>>(hidden, ln1, h1);
  gemm_k<float, float, false, false, false>
      <<<dim3(S_ / BM, (NH_ * HD_) / BN), 256, 0, stream>>>(h1, q_w, nullptr, qb, nullptr, nullptr, nullptr, S_, NH_ * HD_, H_);
  gemm_k<float, float, false, false, false>
      <<<dim3(S_ / BM, (NKV_ * HD_) / BN), 256, 0, stream>>>(h1, k_w, nullptr, kb, nullptr, nullptr, nullptr, S_, NKV_ * HD_, H_);
  gemm_k<float, float, false, false, false>
      <<<dim3(S_ / BM, (NKV_ * HD_) / BN), 256, 0, stream>>>(h1, v_w, nullptr, vb, nullptr, nullptr, nullptr, S_, NKV_ * HD_, H_);
  qknorm_rope_k<<<dim3(S_, NH_ + NKV_), 64, 0, stream>>>(qb, kb, qn, kn, pe);
  attn_k<<<dim3(S_, NH_), 64, 0, stream>>>(qb, kb, vb, ao);
  gemm_k<float, float, false, true, false>
      <<<dim3(S_ / BM, H_ / BN), 256, 0, stream>>>(ao, o_w, hidden, x1, nullptr, nullptr, nullptr, S_, H_, NH_ * HD_);
  rmsnorm_k<<<S_, 256, 0, stream>>>(x1, ln2, h2);
  router_k<<<S_, 256, 0, stream>>>(h2, gate_w, counts, toklist, wlist, sel, pos);
  scan_k<<<1, 64, 0, stream>>>(counts, offs);
  moe_up_k<<<dim3(S_ / BM, I_ / BN, NE_), 256, 0, stream>>>(h2, wg, wu, toklist, counts, offs, act);
  gemm_k<bf16_t, bf16_t, true, false, true>
      <<<dim3(S_ / BM, H_ / BN, NE_), 256, 0, stream>>>(act, wd, nullptr, po, wlist, counts, offs, 0, H_, I_);
  combine_k<<<S_, 256, 0, stream>>>(x1, po, sel, pos, offs, out);
}

// Round 2
// 2152.725 us; speedup vs baseline: 1.7219x; 1.7219x over previous
//
#include <hip/hip_runtime.h>
#include <hip/hip_bf16.h>

#define S_ 1024
#define H_ 2048
#define NH_ 32
#define NKV_ 4
#define HD_ 128
#define NE_ 32
#define TOPK_ 8
#define I_ 768
#define EPS_ 1e-6f

typedef __bf16 bf16_t;
typedef __bf16 bf16x8 __attribute__((ext_vector_type(8)));
typedef float f32x4 __attribute__((ext_vector_type(4)));

#define BM 128
#define BN 128
#define BK 32
#define LDK 40   // BK + 8 pad: 80B row stride, 16B-aligned, conflict-uniform b128

// ---------------- RMSNorm over H (one block per row) ----------------
__global__ __launch_bounds__(256) void rmsnorm_k(const float* __restrict__ x,
                                                 const float* __restrict__ w,
                                                 float* __restrict__ out) {
  int r = blockIdx.x, tid = threadIdx.x;
  const float* xr = x + (size_t)r * H_;
  f32x4 a = *(const f32x4*)(xr + tid * 8);
  f32x4 b = *(const f32x4*)(xr + tid * 8 + 4);
  float ss = 0.f;
#pragma unroll
  for (int i = 0; i < 4; ++i) ss += a[i] * a[i] + b[i] * b[i];
#pragma unroll
  for (int m = 1; m < 64; m <<= 1) ss += __shfl_xor(ss, m);
  __shared__ float wsum[4];
  if ((tid & 63) == 0) wsum[tid >> 6] = ss;
  __syncthreads();
  ss = wsum[0] + wsum[1] + wsum[2] + wsum[3];
  float inv = rsqrtf(ss * (1.0f / H_) + EPS_);
  f32x4 w0 = *(const f32x4*)(w + tid * 8);
  f32x4 w1 = *(const f32x4*)(w + tid * 8 + 4);
  f32x4 o0, o1;
#pragma unroll
  for (int i = 0; i < 4; ++i) { o0[i] = a[i] * inv * w0[i]; o1[i] = b[i] * inv * w1[i]; }
  *(f32x4*)(out + (size_t)r * H_ + tid * 8) = o0;
  *(f32x4*)(out + (size_t)r * H_ + tid * 8 + 4) = o1;
}

// ---------------- weight transpose + bf16 convert: in[R][C] -> out[C][R] ----------------
__global__ __launch_bounds__(256) void transp_k(const float* __restrict__ in,
                                                bf16_t* __restrict__ out, int R, int C) {
  __shared__ float tile[32][33];
  size_t zoff = (size_t)blockIdx.z * R * C;
  in += zoff;
  out += zoff;
  int tx = threadIdx.x & 31, ty = threadIdx.x >> 5;
  int r0 = blockIdx.y * 32, c0 = blockIdx.x * 32;
#pragma unroll
  for (int i = 0; i < 4; ++i)
    tile[ty + i * 8][tx] = in[(size_t)(r0 + ty + i * 8) * C + c0 + tx];
  __syncthreads();
#pragma unroll
  for (int i = 0; i < 4; ++i)
    out[(size_t)(c0 + ty + i * 8) * R + r0 + tx] = (bf16_t)tile[tx][ty + i * 8];
}

// ---------------- generic bf16-MFMA GEMM, 128x128x32 tiles ----------------
// C[M,N] = A[M,K] @ B[K,N]  (+resid) (*per-row scale)
// BT: B supplied pre-transposed bf16 [N][K]
template <typename TA, typename TC, bool EXPERT, bool RESID, bool SCALE, bool BT>
__global__ __launch_bounds__(256, 2) void gemm_k(
    const TA* __restrict__ A, const float* __restrict__ B, const bf16_t* __restrict__ Btr,
    const float* __restrict__ resid, TC* __restrict__ C,
    const float* __restrict__ wlist, const int* __restrict__ counts,
    const int* __restrict__ offsets, int M, int N, int K) {
  int cnt = M;
  const TA* Ab = A;
  const float* Bb = B;
  const bf16_t* Btb = Btr;
  TC* Cb = C;
  const float* wl = nullptr;
  if constexpr (EXPERT) {
    int e = blockIdx.z;
    cnt = counts[e];
    if ((int)(blockIdx.x * BM) >= cnt) return;
    int off = offsets[e];
    Ab = A + (size_t)off * K;
    Cb = C + (size_t)off * N;
    if constexpr (BT) Btb = Btr + (size_t)e * K * N;
    else Bb = B + (size_t)e * K * N;
    if constexpr (SCALE) wl = wlist + (size_t)e * S_;
  }
  __shared__ __align__(16) bf16_t As[BM][LDK];
  __shared__ __align__(16) bf16_t Bs[BN][LDK];   // [n][k]
  int tid = threadIdx.x;
  int lane = tid & 63, wid = tid >> 6;
  int wr = (wid >> 1) * 64, wc = (wid & 1) * 64;
  int fr = lane & 15, kg = (lane >> 4) * 8;
  int m0 = blockIdx.x * BM, n0 = blockIdx.y * BN;

  int sar = tid >> 1, sac = (tid & 1) * 16;          // A stage: 2 thr/row, 16 cols each
  int gar = min(m0 + sar, cnt - 1);
  const TA* aptr = Ab + (size_t)gar * K + sac;
  const float* bptr = nullptr;
  const bf16_t* btptr = nullptr;
  if constexpr (BT) {
    btptr = Btb + (size_t)(n0 + sar) * K + sac;      // 2 thr/row, 16 k each
  } else {
    int sbr = tid >> 3, sbc = (tid & 7) * 16;
    bptr = Bb + (size_t)sbr * N + n0 + sbc;
  }

  f32x4 acc[4][4] = {};

  for (int k0 = 0; k0 < K; k0 += BK) {
    // stage A (convert fp32->bf16 if needed)
    bf16x8 av0, av1;
    if constexpr (sizeof(TA) == 4) {
      f32x4 t0 = *(const f32x4*)(aptr + k0);
      f32x4 t1 = *(const f32x4*)(aptr + k0 + 4);
      f32x4 t2 = *(const f32x4*)(aptr + k0 + 8);
      f32x4 t3 = *(const f32x4*)(aptr + k0 + 12);
#pragma unroll
      for (int i = 0; i < 4; ++i) {
        av0[i] = (__bf16)t0[i]; av0[i + 4] = (__bf16)t1[i];
        av1[i] = (__bf16)t2[i]; av1[i + 4] = (__bf16)t3[i];
      }
    } else {
      av0 = *(const bf16x8*)(aptr + k0);
      av1 = *(const bf16x8*)(aptr + k0 + 8);
    }
    *(bf16x8*)&As[sar][sac] = av0;
    *(bf16x8*)&As[sar][sac + 8] = av1;
    // stage B
    if constexpr (BT) {
      bf16x8 b0 = *(const bf16x8*)(btptr + k0);
      bf16x8 b1 = *(const bf16x8*)(btptr + k0 + 8);
      *(bf16x8*)&Bs[sar][sac] = b0;
      *(bf16x8*)&Bs[sar][sac + 8] = b1;
    } else {
      int sbr = tid >> 3, sbc = (tid & 7) * 16;
      const float* bp = bptr + (size_t)k0 * N;
      f32x4 b0 = *(const f32x4*)(bp);
      f32x4 b1 = *(const f32x4*)(bp + 4);
      f32x4 b2 = *(const f32x4*)(bp + 8);
      f32x4 b3 = *(const f32x4*)(bp + 12);
#pragma unroll
      for (int i = 0; i < 4; ++i) {
        Bs[sbc + i][sbr]      = (bf16_t)b0[i];
        Bs[sbc + 4 + i][sbr]  = (bf16_t)b1[i];
        Bs[sbc + 8 + i][sbr]  = (bf16_t)b2[i];
        Bs[sbc + 12 + i][sbr] = (bf16_t)b3[i];
      }
    }
    __syncthreads();
    bf16x8 af[4], bfv[4];
#pragma unroll
    for (int i = 0; i < 4; ++i) af[i] = *(const bf16x8*)&As[wr + i * 16 + fr][kg];
#pragma unroll
    for (int i = 0; i < 4; ++i) bfv[i] = *(const bf16x8*)&Bs[wc + i * 16 + fr][kg];
#pragma unroll
    for (int mi = 0; mi < 4; ++mi)
#pragma unroll
      for (int ni = 0; ni < 4; ++ni)
        acc[mi][ni] = __builtin_amdgcn_mfma_f32_16x16x32_bf16(af[mi], bfv[ni], acc[mi][ni], 0, 0, 0);
    __syncthreads();
  }
  int rbase = (lane >> 4) * 4;
#pragma unroll
  for (int mi = 0; mi < 4; ++mi)
#pragma unroll
    for (int ni = 0; ni < 4; ++ni)
#pragma unroll
      for (int r = 0; r < 4; ++r) {
        int lr = wr + mi * 16 + rbase + r;
        int gi = m0 + lr;
        if (EXPERT && gi >= cnt) continue;
        int gc = n0 + wc + ni * 16 + fr;
        float v = acc[mi][ni][r];
        if constexpr (SCALE) v *= wl[gi];
        if constexpr (RESID) v += resid[(size_t)gi * N + gc];
        Cb[(size_t)gi * N + gc] = (TC)v;
      }
}

// ---------------- Q/K head-RMSNorm + RoPE (in place) ----------------
__global__ __launch_bounds__(64) void qknorm_rope_k(float* __restrict__ qb, float* __restrict__ kb,
                                                    const float* __restrict__ qn,
                                                    const float* __restrict__ kn,
                                                    const float* __restrict__ pe) {
  int s = blockIdx.x, hh = blockIdx.y, lane = threadIdx.x;
  float* ptr;
  const float* w;
  if (hh < NH_) { ptr = qb + (size_t)s * NH_ * HD_ + hh * HD_; w = qn; }
  else          { ptr = kb + (size_t)s * NKV_ * HD_ + (hh - NH_) * HD_; w = kn; }
  float x0 = ptr[2 * lane], x1 = ptr[2 * lane + 1];
  float ss = x0 * x0 + x1 * x1;
#pragma unroll
  for (int m = 1; m < 64; m <<= 1) ss += __shfl_xor(ss, m);
  float inv = rsqrtf(ss * (1.0f / HD_) + EPS_);
  x0 = x0 * inv * w[2 * lane];
  x1 = x1 * inv * w[2 * lane + 1];
  float ang = pe[(size_t)s * (HD_ / 2) + lane];
  float sn, cs;
  sincosf(ang, &sn, &cs);
  ptr[2 * lane] = x0 * cs - x1 * sn;
  ptr[2 * lane + 1] = x0 * sn + x1 * cs;
}

// ---------------- causal GQA attention v2: fp32, tiled, wave-parallel ----------------
// block = (16 q-rows, 1 head); 4 waves x 4 rows; KV tiles of 64 staged in one
// shared swizzled LDS buffer (K then V). Scores: lanes = 64 kv positions.
// PV: lanes = (j-parity half) x (32 d-chunks). XOR slot swizzle keeps all LDS
// reads <=2-way (free).
#define ATILE 64
__global__ __launch_bounds__(256) void attn2_k(const float* __restrict__ q,
                                               const float* __restrict__ k,
                                               const float* __restrict__ v,
                                               float* __restrict__ o) {
  int h = blockIdx.y;
  int q0 = blockIdx.x * 16;
  int kvh = h >> 3;
  int tid = threadIdx.x, lane = tid & 63, w = tid >> 6;
  __shared__ __align__(16) float kv[ATILE][128];
  __shared__ __align__(16) float qs[16][128];
  __shared__ __align__(16) float ps[4][ATILE][4];  // [wave][j][row]
  {
    const float* qbase = q + (size_t)q0 * (NH_ * HD_) + (size_t)h * HD_;
#pragma unroll
    for (int i = 0; i < 8; ++i) {
      int flat = tid + i * 256;
      int r = flat >> 7, c = flat & 127;
      qs[r][c] = qbase[(size_t)r * (NH_ * HD_) + c];
    }
  }
  float m[4], l[4];
  f32x4 oacc[4] = {};
  int qrow[4];
#pragma unroll
  for (int r = 0; r < 4; ++r) { m[r] = -3.0e38f; l[r] = 0.f; qrow[r] = q0 + w * 4 + r; }
  int nt = q0 / ATILE + 1;
  const float scale = 0.08838834764831845f;  // 1/sqrt(128)
  __syncthreads();
  for (int t = 0; t < nt; ++t) {
    // ---- stage K tile (16B-slot XOR swizzle) ----
#pragma unroll
    for (int i = 0; i < 8; ++i) {
      int flat = tid + i * 256;
      int r = flat >> 5, c = flat & 31;
      f32x4 val = *(const f32x4*)(k + (((size_t)(t * ATILE + r) * NKV_ + kvh) << 7) + c * 4);
      int cs = c ^ (r & 31);
      *(f32x4*)&kv[r][cs * 4] = val;
    }
    __syncthreads();
    // ---- scores: lane = kv position ----
    float sacc[4] = {0.f, 0.f, 0.f, 0.f};
    {
      int j = lane;
      for (int c = 0; c < 32; ++c) {
        int cs = c ^ (j & 31);
        f32x4 kvv = *(const f32x4*)&kv[j][cs * 4];
#pragma unroll
        for (int r = 0; r < 4; ++r) {
          f32x4 qv = *(const f32x4*)&qs[w * 4 + r][c * 4];
          sacc[r] += qv[0] * kvv[0] + qv[1] * kvv[1] + qv[2] * kvv[2] + qv[3] * kvv[3];
        }
      }
      int kj = t * ATILE + j;
#pragma unroll
      for (int r = 0; r < 4; ++r)
        sacc[r] = (kj <= qrow[r]) ? sacc[r] * scale : -3.0e38f;
    }
    // ---- online softmax (per wave, per row) ----
    float pj[4], sc[4];
#pragma unroll
    for (int r = 0; r < 4; ++r) {
      float tm = sacc[r];
#pragma unroll
      for (int mm = 1; mm < 64; mm <<= 1) tm = fmaxf(tm, __shfl_xor(tm, mm));
      float mn = fmaxf(m[r], tm);
      float pv = __expf(sacc[r] - mn);
      float ts = pv;
#pragma unroll
      for (int mm = 1; mm < 64; mm <<= 1) ts += __shfl_xor(ts, mm);
      sc[r] = __expf(m[r] - mn);
      l[r] = l[r] * sc[r] + ts;
      m[r] = mn;
      pj[r] = pv;
    }
    {
      f32x4 pw = {pj[0], pj[1], pj[2], pj[3]};
      *(f32x4*)&ps[w][lane][0] = pw;
    }
#pragma unroll
    for (int r = 0; r < 4; ++r)
#pragma unroll
      for (int i = 0; i < 4; ++i) oacc[r][i] *= sc[r];
    __syncthreads();
    // ---- stage V tile (same buffer) ----
#pragma unroll
    for (int i = 0; i < 8; ++i) {
      int flat = tid + i * 256;
      int r = flat >> 5, c = flat & 31;
      f32x4 val = *(const f32x4*)(v + (((size_t)(t * ATILE + r) * NKV_ + kvh) << 7) + c * 4);
      int cs = c ^ (r & 31);
      *(f32x4*)&kv[r][cs * 4] = val;
    }
    __syncthreads();
    // ---- PV: lane = (j-half, d-chunk) ----
    {
      int jh = lane >> 5, dc = lane & 31;
      for (int jj = 0; jj < ATILE; jj += 2) {
        int j = jj + jh;
        int cs = dc ^ (j & 31);
        f32x4 vv = *(const f32x4*)&kv[j][cs * 4];
        f32x4 pv4 = *(const f32x4*)&ps[w][j][0];
#pragma unroll
        for (int r = 0; r < 4; ++r) {
          oacc[r][0] += pv4[r] * vv[0];
          oacc[r][1] += pv4[r] * vv[1];
          oacc[r][2] += pv4[r] * vv[2];
          oacc[r][3] += pv4[r] * vv[3];
        }
      }
    }
    __syncthreads();
  }
  // combine j-parity halves, normalize, write
#pragma unroll
  for (int r = 0; r < 4; ++r)
#pragma unroll
    for (int i = 0; i < 4; ++i) oacc[r][i] += __shfl_xor(oacc[r][i], 32);
  if (lane < 32) {
    int dc = lane;
#pragma unroll
    for (int r = 0; r < 4; ++r) {
      float inv = 1.0f / l[r];
      f32x4 ov;
#pragma unroll
      for (int i = 0; i < 4; ++i) ov[i] = oacc[r][i] * inv;
      *(f32x4*)(o + (size_t)qrow[r] * (NH_ * HD_) + (size_t)h * HD_ + dc * 4) = ov;
    }
  }
}

// ---------------- router ----------------
__global__ __launch_bounds__(256) void router_k(const float* __restrict__ h2,
                                                const float* __restrict__ gw,
                                                int* __restrict__ counts, int* __restrict__ toklist,
                                                float* __restrict__ wlist, int* __restrict__ sel,
                                                int* __restrict__ pos) {
  int t = blockIdx.x, tid = threadIdx.x;
  int e = tid & 31, grp = tid >> 5;
  float acc = 0.f;
  for (int kk = grp; kk < H_; kk += 8)
    acc += h2[(size_t)t * H_ + kk] * gw[(size_t)kk * NE_ + e];
  __shared__ float part[8][32];
  part[grp][e] = acc;
  __syncthreads();
  if (tid == 0) {
    float lg[NE_];
    for (int ee = 0; ee < NE_; ++ee) {
      float s = 0.f;
      for (int g = 0; g < 8; ++g) s += part[g][ee];
      lg[ee] = s;
    }
    float m = lg[0];
    for (int ee = 1; ee < NE_; ++ee) m = fmaxf(m, lg[ee]);
    for (int ee = 0; ee < NE_; ++ee) lg[ee] = __expf(lg[ee] - m);
    bool used[NE_] = {};
    float rw[TOPK_]; int se[TOPK_]; float tot = 0.f;
    for (int kk = 0; kk < TOPK_; ++kk) {
      float best = -1.f; int bi = 0;
      for (int ee = 0; ee < NE_; ++ee)
        if (!used[ee] && lg[ee] > best) { best = lg[ee]; bi = ee; }
      used[bi] = true; se[kk] = bi; rw[kk] = best; tot += best;
    }
    float itot = 1.0f / tot;
    for (int kk = 0; kk < TOPK_; ++kk) {
      int ee = se[kk];
      int pp = atomicAdd(&counts[ee], 1);
      toklist[ee * S_ + pp] = t;
      wlist[ee * S_ + pp] = rw[kk] * itot;
      sel[t * TOPK_ + kk] = ee;
      pos[t * TOPK_ + kk] = pp;
    }
  }
}

__global__ void scan_k(const int* __restrict__ counts, int* __restrict__ offsets) {
  if (threadIdx.x == 0 && blockIdx.x == 0) {
    int o = 0;
    for (int e = 0; e < NE_; ++e) { offsets[e] = o; o += counts[e]; }
    offsets[NE_] = o;
  }
}

// ---------------- MoE up: ACT[slot,i] = silu(h2@wg) * (h2@wu), bf16 out ----------------
template <bool BT>
__global__ __launch_bounds__(256, 1) void moe_up_k(const float* __restrict__ h2,
                                                   const float* __restrict__ wg,
                                                   const float* __restrict__ wu,
                                                   const bf16_t* __restrict__ wgT,
                                                   const bf16_t* __restrict__ wuT,
                                                   const int* __restrict__ toklist,
                                                   const int* __restrict__ counts,
                                                   const int* __restrict__ offsets,
                                                   bf16_t* __restrict__ act) {
  int eidx = blockIdx.z;
  int cnt = counts[eidx];
  int m0 = blockIdx.x * BM;
  if (m0 >= cnt) return;
  int n0 = blockIdx.y * BN;
  const int* toks = toklist + (size_t)eidx * S_;
  __shared__ __align__(16) bf16_t As[BM][LDK];
  __shared__ __align__(16) bf16_t Gs[BN][LDK];
  __shared__ __align__(16) bf16_t Us[BN][LDK];
  int tid = threadIdx.x, lane = tid & 63, wid = tid >> 6;
  int wr = (wid >> 1) * 64, wc = (wid & 1) * 64;
  int fr = lane & 15, kg = (lane >> 4) * 8;
  int sar = tid >> 1, sac = (tid & 1) * 16;
  int gi_l = min(m0 + sar, cnt - 1);
  const float* aptr = h2 + (size_t)toks[gi_l] * H_ + sac;
  const float* gptr = nullptr;
  const float* uptr = nullptr;
  const bf16_t* gtp = nullptr;
  const bf16_t* utp = nullptr;
  if constexpr (BT) {
    gtp = wgT + (size_t)eidx * H_ * I_ + (size_t)(n0 + sar) * H_ + sac;
    utp = wuT + (size_t)eidx * H_ * I_ + (size_t)(n0 + sar) * H_ + sac;
  } else {
    int sbr = tid >> 3, sbc = (tid & 7) * 16;
    gptr = wg + (size_t)eidx * H_ * I_ + (size_t)sbr * I_ + n0 + sbc;
    uptr = wu + (size_t)eidx * H_ * I_ + (size_t)sbr * I_ + n0 + sbc;
  }
  f32x4 accg[4][4] = {}, accu[4][4] = {};
  for (int k0 = 0; k0 < H_; k0 += BK) {
    {
      f32x4 t0 = *(const f32x4*)(aptr + k0);
      f32x4 t1 = *(const f32x4*)(aptr + k0 + 4);
      f32x4 t2 = *(const f32x4*)(aptr + k0 + 8);
      f32x4 t3 = *(const f32x4*)(aptr + k0 + 12);
      bf16x8 av0, av1;
#pragma unroll
      for (int i = 0; i < 4; ++i) {
        av0[i] = (__bf16)t0[i]; av0[i + 4] = (__bf16)t1[i];
        av1[i] = (__bf16)t2[i]; av1[i + 4] = (__bf16)t3[i];
      }
      *(bf16x8*)&As[sar][sac] = av0;
      *(bf16x8*)&As[sar][sac + 8] = av1;
    }
    if constexpr (BT) {
      bf16x8 g0 = *(const bf16x8*)(gtp + k0);
      bf16x8 g1 = *(const bf16x8*)(gtp + k0 + 8);
      *(bf16x8*)&Gs[sar][sac] = g0;
      *(bf16x8*)&Gs[sar][sac + 8] = g1;
      bf16x8 u0 = *(const bf16x8*)(utp + k0);
      bf16x8 u1 = *(const bf16x8*)(utp + k0 + 8);
      *(bf16x8*)&Us[sar][sac] = u0;
      *(bf16x8*)&Us[sar][sac + 8] = u1;
    } else {
      int sbr = tid >> 3, sbc = (tid & 7) * 16;
      {
        const float* bp = gptr + (size_t)k0 * I_;
        f32x4 b0 = *(const f32x4*)(bp);
        f32x4 b1 = *(const f32x4*)(bp + 4);
        f32x4 b2 = *(const f32x4*)(bp + 8);
        f32x4 b3 = *(const f32x4*)(bp + 12);
#pragma unroll
        for (int i = 0; i < 4; ++i) {
          Gs[sbc + i][sbr]      = (bf16_t)b0[i];
          Gs[sbc + 4 + i][sbr]  = (bf16_t)b1[i];
          Gs[sbc + 8 + i][sbr]  = (bf16_t)b2[i];
          Gs[sbc + 12 + i][sbr] = (bf16_t)b3[i];
        }
      }
      {
        const float* bp = uptr + (size_t)k0 * I_;
        f32x4 b0 = *(const f32x4*)(bp);
        f32x4 b1 = *(const f32x4*)(bp + 4);
        f32x4 b2 = *(const f32x4*)(bp + 8);
        f32x4 b3 = *(const f32x4*)(bp + 12);
#pragma unroll
        for (int i = 0; i < 4; ++i) {
          Us[sbc + i][sbr]      = (bf16_t)b0[i];
          Us[sbc + 4 + i][sbr]  = (bf16_t)b1[i];
          Us[sbc + 8 + i][sbr]  = (bf16_t)b2[i];
          Us[sbc + 12 + i][sbr] = (bf16_t)b3[i];
        }
      }
    }
    __syncthreads();
    bf16x8 af[4], gf[4], uf[4];
#pragma unroll
    for (int i = 0; i < 4; ++i) af[i] = *(const bf16x8*)&As[wr + i * 16 + fr][kg];
#pragma unroll
    for (int i = 0; i < 4; ++i) gf[i] = *(const bf16x8*)&Gs[wc + i * 16 + fr][kg];
#pragma unroll
    for (int i = 0; i < 4; ++i) uf[i] = *(const bf16x8*)&Us[wc + i * 16 + fr][kg];
#pragma unroll
    for (int mi = 0; mi < 4; ++mi)
#pragma unroll
      for (int ni = 0; ni < 4; ++ni) {
        accg[mi][ni] = __builtin_amdgcn_mfma_f32_16x16x32_bf16(af[mi], gf[ni], accg[mi][ni], 0, 0, 0);
        accu[mi][ni] = __builtin_amdgcn_mfma_f32_16x16x32_bf16(af[mi], uf[ni], accu[mi][ni], 0, 0, 0);
      }
    __syncthreads();
  }
  int rbase = (lane >> 4) * 4;
  int slotbase = offsets[eidx];
#pragma unroll
  for (int mi = 0; mi < 4; ++mi)
#pragma unroll
    for (int ni = 0; ni < 4; ++ni)
#pragma unroll
      for (int r = 0; r < 4; ++r) {
        int lr = wr + mi * 16 + rbase + r;
        int gi = m0 + lr;
        if (gi < cnt) {
          float g = accg[mi][ni][r], u = accu[mi][ni][r];
          float sig = 1.0f / (1.0f + __expf(-g));
          float a = g * sig * u;
          act[(size_t)(slotbase + gi) * I_ + n0 + wc + ni * 16 + fr] = (bf16_t)a;
        }
      }
}

// ---------------- combine ----------------
__global__ __launch_bounds__(256) void combine_k(const float* __restrict__ x1,
                                                 const bf16_t* __restrict__ pairout,
                                                 const int* __restrict__ sel,
                                                 const int* __restrict__ pos,
                                                 const int* __restrict__ offsets,
                                                 float* __restrict__ out) {
  int t = blockIdx.x, tid = threadIdx.x;
  int slots[TOPK_];
#pragma unroll
  for (int kk = 0; kk < TOPK_; ++kk)
    slots[kk] = offsets[sel[t * TOPK_ + kk]] + pos[t * TOPK_ + kk];
  int c = tid * 8;
  f32x4 s0 = *(const f32x4*)(x1 + (size_t)t * H_ + c);
  f32x4 s1 = *(const f32x4*)(x1 + (size_t)t * H_ + c + 4);
#pragma unroll
  for (int kk = 0; kk < TOPK_; ++kk) {
    bf16x8 pv = *(const bf16x8*)(pairout + (size_t)slots[kk] * H_ + c);
#pragma unroll
    for (int i = 0; i < 4; ++i) { s0[i] += (float)pv[i]; s1[i] += (float)pv[i + 4]; }
  }
  *(f32x4*)(out + (size_t)t * H_ + c) = s0;
  *(f32x4*)(out + (size_t)t * H_ + c + 4) = s1;
}

extern "C" void kernel_launch(void* const* d_in, const int* in_sizes, int n_in,
                              void* d_out, int out_size, void* d_ws, size_t ws_size,
                              hipStream_t stream) {
  const float* hidden = (const float*)d_in[0];
  const float* pe     = (const float*)d_in[1];
  const float* ln1    = (const float*)d_in[4];
  const float* ln2    = (const float*)d_in[5];
  const float* q_w    = (const float*)d_in[6];
  const float* k_w    = (const float*)d_in[7];
  const float* v_w    = (const float*)d_in[8];
  const float* o_w    = (const float*)d_in[9];
  const float* qn     = (const float*)d_in[10];
  const float* kn     = (const float*)d_in[11];
  const float* gate_w = (const float*)d_in[12];
  const float* wg     = (const float*)d_in[13];
  const float* wu     = (const float*)d_in[14];
  const float* wd     = (const float*)d_in[15];
  float* out = (float*)d_out;

  char* p = (char*)d_ws;
  auto alloc = [&](size_t bytes) {
    char* r = p;
    p += (bytes + 255) & ~(size_t)255;
    return r;
  };
  float*  h1      = (float*)alloc((size_t)S_ * H_ * 4);
  float*  qb      = (float*)alloc((size_t)S_ * NH_ * HD_ * 4);
  float*  kb      = (float*)alloc((size_t)S_ * NKV_ * HD_ * 4);
  float*  vb      = (float*)alloc((size_t)S_ * NKV_ * HD_ * 4);
  float*  ao      = (float*)alloc((size_t)S_ * NH_ * HD_ * 4);
  float*  x1      = (float*)alloc((size_t)S_ * H_ * 4);
  float*  h2      = (float*)alloc((size_t)S_ * H_ * 4);
  bf16_t* act     = (bf16_t*)alloc((size_t)S_ * TOPK_ * I_ * 2);
  bf16_t* po      = (bf16_t*)alloc((size_t)S_ * TOPK_ * H_ * 2);
  int*    counts  = (int*)alloc(NE_ * 4);
  int*    offs    = (int*)alloc((NE_ + 1) * 4);
  int*    toklist = (int*)alloc((size_t)NE_ * S_ * 4);
  float*  wlist   = (float*)alloc((size_t)NE_ * S_ * 4);
  int*    sel     = (int*)alloc((size_t)S_ * TOPK_ * 4);
  int*    pos     = (int*)alloc((size_t)S_ * TOPK_ * 4);
  // pre-transposed bf16 weights (only used if ws fits)
  bf16_t* qwT = (bf16_t*)alloc((size_t)H_ * (NH_ * HD_) * 2);
  bf16_t* kwT = (bf16_t*)alloc((size_t)H_ * (NKV_ * HD_) * 2);
  bf16_t* vwT = (bf16_t*)alloc((size_t)H_ * (NKV_ * HD_) * 2);
  bf16_t* owT = (bf16_t*)alloc((size_t)(NH_ * HD_) * H_ * 2);
  bf16_t* wgT = (bf16_t*)alloc((size_t)NE_ * H_ * I_ * 2);
  bf16_t* wuT = (bf16_t*)alloc((size_t)NE_ * H_ * I_ * 2);
  bf16_t* wdT = (bf16_t*)alloc((size_t)NE_ * I_ * H_ * 2);
  bool useBT = ((size_t)(p - (char*)d_ws) <= ws_size);

  hipMemsetAsync(counts, 0, NE_ * 4, stream);

  if (useBT) {
    transp_k<<<dim3((NH_ * HD_) / 32, H_ / 32, 1), 256, 0, stream>>>(q_w, qwT, H_, NH_ * HD_);
    transp_k<<<dim3((NKV_ * HD_) / 32, H_ / 32, 1), 256, 0, stream>>>(k_w, kwT, H_, NKV_ * HD_);
    transp_k<<<dim3((NKV_ * HD_) / 32, H_ / 32, 1), 256, 0, stream>>>(v_w, vwT, H_, NKV_ * HD_);
    transp_k<<<dim3(H_ / 32, (NH_ * HD_) / 32, 1), 256, 0, stream>>>(o_w, owT, NH_ * HD_, H_);
    transp_k<<<dim3(I_ / 32, H_ / 32, NE_), 256, 0, stream>>>(wg, wgT, H_, I_);
    transp_k<<<dim3(I_ / 32, H_ / 32, NE_), 256, 0, stream>>>(wu, wuT, H_, I_);
    transp_k<<<dim3(H_ / 32, I_ / 32, NE_), 256, 0, stream>>>(wd, wdT, I_, H_);
  }

  rmsnorm_k<<<S_, 256, 0, stream>>>(hidden, ln1, h1);
  if (useBT) {
    gemm_k<float, float, false, false, false, true>
        <<<dim3(S_ / BM, (NH_ * HD_) / BN), 256, 0, stream>>>(h1, nullptr, qwT, nullptr, qb, nullptr, nullptr, nullptr, S_, NH_ * HD_, H_);
    gemm_k<float, float, false, false, false, true>
        <<<dim3(S_ / BM, (NKV_ * HD_) / BN), 256, 0, stream>>>(h1, nullptr, kwT, nullptr, kb, nullptr, nullptr, nullptr, S_, NKV_ * HD_, H_);
    gemm_k<float, float, false, false, false, true>
        <<<dim3(S_ / BM, (NKV_ * HD_) / BN), 256, 0, stream>>>(h1, nullptr, vwT, nullptr, vb, nullptr, nullptr, nullptr, S_, NKV_ * HD_, H_);
  } else {
    gemm_k<float, float, false, false, false, false>
        <<<dim3(S_ / BM, (NH_ * HD_) / BN), 256, 0, stream>>>(h1, q_w, nullptr, nullptr, qb, nullptr, nullptr, nullptr, S_, NH_ * HD_, H_);
    gemm_k<float, float, false, false, false, false>
        <<<dim3(S_ / BM, (NKV_ * HD_) / BN), 256, 0, stream>>>(h1, k_w, nullptr, nullptr, kb, nullptr, nullptr, nullptr, S_, NKV_ * HD_, H_);
    gemm_k<float, float, false, false, false, false>
        <<<dim3(S_ / BM, (NKV_ * HD_) / BN), 256, 0, stream>>>(h1, v_w, nullptr, nullptr, vb, nullptr, nullptr, nullptr, S_, NKV_ * HD_, H_);
  }
  qknorm_rope_k<<<dim3(S_, NH_ + NKV_), 64, 0, stream>>>(qb, kb, qn, kn, pe);
  attn2_k<<<dim3(S_ / 16, NH_), 256, 0, stream>>>(qb, kb, vb, ao);
  if (useBT) {
    gemm_k<float, float, false, true, false, true>
        <<<dim3(S_ / BM, H_ / BN), 256, 0, stream>>>(ao, nullptr, owT, hidden, x1, nullptr, nullptr, nullptr, S_, H_, NH_ * HD_);
  } else {
    gemm_k<float, float, false, true, false, false>
        <<<dim3(S_ / BM, H_ / BN), 256, 0, stream>>>(ao, o_w, nullptr, hidden, x1, nullptr, nullptr, nullptr, S_, H_, NH_ * HD_);
  }
  rmsnorm_k<<<S_, 256, 0, stream>>>(x1, ln2, h2);
  router_k<<<S_, 256, 0, stream>>>(h2, gate_w, counts, toklist, wlist, sel, pos);
  scan_k<<<1, 64, 0, stream>>>(counts, offs);
  if (useBT) {
    moe_up_k<true><<<dim3(S_ / BM, I_ / BN, NE_), 256, 0, stream>>>(h2, nullptr, nullptr, wgT, wuT, toklist, counts, offs, act);
    gemm_k<bf16_t, bf16_t, true, false, true, true>
        <<<dim3(S_ / BM, H_ / BN, NE_), 256, 0, stream>>>(act, nullptr, wdT, nullptr, po, wlist, counts, offs, 0, H_, I_);
  } else {
    moe_up_k<false><<<dim3(S_ / BM, I_ / BN, NE_), 256, 0, stream>>>(h2, wg, wu, nullptr, nullptr, toklist, counts, offs, act);
    gemm_k<bf16_t, bf16_t, true, false, true, false>
        <<<dim3(S_ / BM, H_ / BN, NE_), 256, 0, stream>>>(act, wd, nullptr, nullptr, po, wlist, counts, offs, 0, H_, I_);
  }
  combine_k<<<S_, 256, 0, stream>>>(x1, po, sel, pos, offs, out);
}

// Round 3
// 1753.328 us; speedup vs baseline: 2.1142x; 1.2278x over previous
//
#include <hip/hip_runtime.h>
#include <hip/hip_bf16.h>

#define S_ 1024
#define H_ 2048
#define NH_ 32
#define NKV_ 4
#define HD_ 128
#define NE_ 32
#define TOPK_ 8
#define I_ 768
#define EPS_ 1e-6f

typedef __bf16 bf16_t;
typedef __bf16 bf16x8 __attribute__((ext_vector_type(8)));
typedef float f32x4 __attribute__((ext_vector_type(4)));
typedef float f32x16 __attribute__((ext_vector_type(16)));
typedef unsigned short u16_t;
typedef unsigned int uint2v __attribute__((ext_vector_type(2)));
typedef unsigned int uint4v __attribute__((ext_vector_type(4)));

#define BM 128
#define BN 128
#define BK 32
#define LDK 40   // BK + 8 pad: 80B row stride, 16B-aligned, conflict-uniform b128

static __device__ __forceinline__ u16_t f2u(float x) {
  return __builtin_bit_cast(u16_t, (__bf16)x);
}
static __device__ __forceinline__ float u2f(u16_t u) {
  return (float)__builtin_bit_cast(__bf16, u);
}

// ---------------- RMSNorm over H (one block per row) ----------------
__global__ __launch_bounds__(256) void rmsnorm_k(const float* __restrict__ x,
                                                 const float* __restrict__ w,
                                                 float* __restrict__ out) {
  int r = blockIdx.x, tid = threadIdx.x;
  const float* xr = x + (size_t)r * H_;
  f32x4 a = *(const f32x4*)(xr + tid * 8);
  f32x4 b = *(const f32x4*)(xr + tid * 8 + 4);
  float ss = 0.f;
#pragma unroll
  for (int i = 0; i < 4; ++i) ss += a[i] * a[i] + b[i] * b[i];
#pragma unroll
  for (int m = 1; m < 64; m <<= 1) ss += __shfl_xor(ss, m);
  __shared__ float wsum[4];
  if ((tid & 63) == 0) wsum[tid >> 6] = ss;
  __syncthreads();
  ss = wsum[0] + wsum[1] + wsum[2] + wsum[3];
  float inv = rsqrtf(ss * (1.0f / H_) + EPS_);
  f32x4 w0 = *(const f32x4*)(w + tid * 8);
  f32x4 w1 = *(const f32x4*)(w + tid * 8 + 4);
  f32x4 o0, o1;
#pragma unroll
  for (int i = 0; i < 4; ++i) { o0[i] = a[i] * inv * w0[i]; o1[i] = b[i] * inv * w1[i]; }
  *(f32x4*)(out + (size_t)r * H_ + tid * 8) = o0;
  *(f32x4*)(out + (size_t)r * H_ + tid * 8 + 4) = o1;
}

// ---------------- weight transpose + bf16 convert: in[R][C] -> out[C][R] ----------------
__global__ __launch_bounds__(256) void transp_k(const float* __restrict__ in,
                                                bf16_t* __restrict__ out, int R, int C) {
  __shared__ float tile[32][33];
  size_t zoff = (size_t)blockIdx.z * R * C;
  in += zoff;
  out += zoff;
  int tx = threadIdx.x & 31, ty = threadIdx.x >> 5;
  int r0 = blockIdx.y * 32, c0 = blockIdx.x * 32;
#pragma unroll
  for (int i = 0; i < 4; ++i)
    tile[ty + i * 8][tx] = in[(size_t)(r0 + ty + i * 8) * C + c0 + tx];
  __syncthreads();
#pragma unroll
  for (int i = 0; i < 4; ++i)
    out[(size_t)(c0 + ty + i * 8) * R + r0 + tx] = (bf16_t)tile[tx][ty + i * 8];
}

// ---------------- generic bf16-MFMA GEMM, 128x128x32 tiles ----------------
template <typename TA, typename TC, bool EXPERT, bool RESID, bool SCALE, bool BT>
__global__ __launch_bounds__(256, 2) void gemm_k(
    const TA* __restrict__ A, const float* __restrict__ B, const bf16_t* __restrict__ Btr,
    const float* __restrict__ resid, TC* __restrict__ C,
    const float* __restrict__ wlist, const int* __restrict__ counts,
    const int* __restrict__ offsets, int M, int N, int K) {
  int cnt = M;
  const TA* Ab = A;
  const float* Bb = B;
  const bf16_t* Btb = Btr;
  TC* Cb = C;
  const float* wl = nullptr;
  if constexpr (EXPERT) {
    int e = blockIdx.z;
    cnt = counts[e];
    if ((int)(blockIdx.x * BM) >= cnt) return;
    int off = offsets[e];
    Ab = A + (size_t)off * K;
    Cb = C + (size_t)off * N;
    if constexpr (BT) Btb = Btr + (size_t)e * K * N;
    else Bb = B + (size_t)e * K * N;
    if constexpr (SCALE) wl = wlist + (size_t)e * S_;
  }
  __shared__ __align__(16) bf16_t As[BM][LDK];
  __shared__ __align__(16) bf16_t Bs[BN][LDK];   // [n][k]
  int tid = threadIdx.x;
  int lane = tid & 63, wid = tid >> 6;
  int wr = (wid >> 1) * 64, wc = (wid & 1) * 64;
  int fr = lane & 15, kg = (lane >> 4) * 8;
  int m0 = blockIdx.x * BM, n0 = blockIdx.y * BN;

  int sar = tid >> 1, sac = (tid & 1) * 16;
  int gar = min(m0 + sar, cnt - 1);
  const TA* aptr = Ab + (size_t)gar * K + sac;
  const float* bptr = nullptr;
  const bf16_t* btptr = nullptr;
  if constexpr (BT) {
    btptr = Btb + (size_t)(n0 + sar) * K + sac;
  } else {
    int sbr = tid >> 3, sbc = (tid & 7) * 16;
    bptr = Bb + (size_t)sbr * N + n0 + sbc;
  }

  f32x4 acc[4][4] = {};

  for (int k0 = 0; k0 < K; k0 += BK) {
    bf16x8 av0, av1;
    if constexpr (sizeof(TA) == 4) {
      f32x4 t0 = *(const f32x4*)(aptr + k0);
      f32x4 t1 = *(const f32x4*)(aptr + k0 + 4);
      f32x4 t2 = *(const f32x4*)(aptr + k0 + 8);
      f32x4 t3 = *(const f32x4*)(aptr + k0 + 12);
#pragma unroll
      for (int i = 0; i < 4; ++i) {
        av0[i] = (__bf16)t0[i]; av0[i + 4] = (__bf16)t1[i];
        av1[i] = (__bf16)t2[i]; av1[i + 4] = (__bf16)t3[i];
      }
    } else {
      av0 = *(const bf16x8*)(aptr + k0);
      av1 = *(const bf16x8*)(aptr + k0 + 8);
    }
    *(bf16x8*)&As[sar][sac] = av0;
    *(bf16x8*)&As[sar][sac + 8] = av1;
    if constexpr (BT) {
      bf16x8 b0 = *(const bf16x8*)(btptr + k0);
      bf16x8 b1 = *(const bf16x8*)(btptr + k0 + 8);
      *(bf16x8*)&Bs[sar][sac] = b0;
      *(bf16x8*)&Bs[sar][sac + 8] = b1;
    } else {
      int sbr = tid >> 3, sbc = (tid & 7) * 16;
      const float* bp = bptr + (size_t)k0 * N;
      f32x4 b0 = *(const f32x4*)(bp);
      f32x4 b1 = *(const f32x4*)(bp + 4);
      f32x4 b2 = *(const f32x4*)(bp + 8);
      f32x4 b3 = *(const f32x4*)(bp + 12);
#pragma unroll
      for (int i = 0; i < 4; ++i) {
        Bs[sbc + i][sbr]      = (bf16_t)b0[i];
        Bs[sbc + 4 + i][sbr]  = (bf16_t)b1[i];
        Bs[sbc + 8 + i][sbr]  = (bf16_t)b2[i];
        Bs[sbc + 12 + i][sbr] = (bf16_t)b3[i];
      }
    }
    __syncthreads();
    bf16x8 af[4], bfv[4];
#pragma unroll
    for (int i = 0; i < 4; ++i) af[i] = *(const bf16x8*)&As[wr + i * 16 + fr][kg];
#pragma unroll
    for (int i = 0; i < 4; ++i) bfv[i] = *(const bf16x8*)&Bs[wc + i * 16 + fr][kg];
#pragma unroll
    for (int mi = 0; mi < 4; ++mi)
#pragma unroll
      for (int ni = 0; ni < 4; ++ni)
        acc[mi][ni] = __builtin_amdgcn_mfma_f32_16x16x32_bf16(af[mi], bfv[ni], acc[mi][ni], 0, 0, 0);
    __syncthreads();
  }
  int rbase = (lane >> 4) * 4;
#pragma unroll
  for (int mi = 0; mi < 4; ++mi)
#pragma unroll
    for (int ni = 0; ni < 4; ++ni)
#pragma unroll
      for (int r = 0; r < 4; ++r) {
        int lr = wr + mi * 16 + rbase + r;
        int gi = m0 + lr;
        if (EXPERT && gi >= cnt) continue;
        int gc = n0 + wc + ni * 16 + fr;
        float v = acc[mi][ni][r];
        if constexpr (SCALE) v *= wl[gi];
        if constexpr (RESID) v += resid[(size_t)gi * N + gc];
        Cb[(size_t)gi * N + gc] = (TC)v;
      }
}

// ---------------- Q/K head-RMSNorm + RoPE (in place) ----------------
__global__ __launch_bounds__(64) void qknorm_rope_k(float* __restrict__ qb, float* __restrict__ kb,
                                                    const float* __restrict__ qn,
                                                    const float* __restrict__ kn,
                                                    const float* __restrict__ pe) {
  int s = blockIdx.x, hh = blockIdx.y, lane = threadIdx.x;
  float* ptr;
  const float* w;
  if (hh < NH_) { ptr = qb + (size_t)s * NH_ * HD_ + hh * HD_; w = qn; }
  else          { ptr = kb + (size_t)s * NKV_ * HD_ + (hh - NH_) * HD_; w = kn; }
  float x0 = ptr[2 * lane], x1 = ptr[2 * lane + 1];
  float ss = x0 * x0 + x1 * x1;
#pragma unroll
  for (int m = 1; m < 64; m <<= 1) ss += __shfl_xor(ss, m);
  float inv = rsqrtf(ss * (1.0f / HD_) + EPS_);
  x0 = x0 * inv * w[2 * lane];
  x1 = x1 * inv * w[2 * lane + 1];
  float ang = pe[(size_t)s * (HD_ / 2) + lane];
  float sn, cs;
  sincosf(ang, &sn, &cs);
  ptr[2 * lane] = x0 * cs - x1 * sn;
  ptr[2 * lane + 1] = x0 * sn + x1 * cs;
}

// ---------------- attention v3: split-bf16 MFMA (fp32-accurate), causal GQA ----------------
// block = 128 q-rows x 1 head; 4 waves x 32 rows (mfma_f32_32x32x16_bf16).
// Swapped QK (A=K, B=Q regs) -> lane owns one q-row's scores; P->PV A-frag via
// in-register bf16 pack + shfl_xor(32). K LDS [kv][hi/lo][dim], V LDS transposed
// [dim][hi/lo][kv], XOR slot swizzles. Each x.y ~ hh+hl+lh 3-pass split product.
#define AQB 128
#define AKV 64
__global__ __launch_bounds__(256, 2) void attn3_k(const float* __restrict__ q,
                                                  const float* __restrict__ k,
                                                  const float* __restrict__ v,
                                                  float* __restrict__ o) {
  int h = blockIdx.y, qblk = blockIdx.x;
  int q0 = qblk * AQB;
  int kvh = h >> 3;
  int tid = threadIdx.x, lane = tid & 63, w = tid >> 6;
  int g = lane >> 5, c32 = lane & 31;
  __shared__ __align__(16) u16_t Kl[AKV * 256];   // [kv][hilo*128+dim] swizzled (32KB)
  __shared__ __align__(16) u16_t Vl[128 * 128];   // [dim][hilo*64+kv] swizzled (32KB)

  int qrow = q0 + w * 32 + c32;
  const float scale = 0.08838834764831845f;  // 1/sqrt(128)

  // Q fragments in registers (scale folded in), split hi/lo
  bf16x8 qh[8], ql[8];
  {
    const float* qp = q + ((size_t)qrow * NH_ + h) * HD_;
#pragma unroll
    for (int ks = 0; ks < 8; ++ks) {
      int db = g * 8 + ks * 16;
      f32x4 a = *(const f32x4*)(qp + db);
      f32x4 b = *(const f32x4*)(qp + db + 4);
#pragma unroll
      for (int j = 0; j < 8; ++j) {
        float x = (j < 4 ? a[j & 3] : b[j & 3]) * scale;
        __bf16 hb = (__bf16)x;
        qh[ks][j] = hb;
        ql[ks][j] = (__bf16)(x - (float)hb);
      }
    }
  }

  f32x16 accO[4] = {};
  float m = -3.0e38f, l = 0.f;
  int last_t = (q0 + w * 32 + 31) >> 6;
  int NT = 2 * qblk + 2;

  for (int t = 0; t < NT; ++t) {
    int kv0 = t * AKV;
    __syncthreads();
    // ---- stage K: [kv][hl][dim], slot(16B)= (hl*16 + dim>>3) ^ (kv&31) ----
#pragma unroll
    for (int i = 0; i < 8; ++i) {
      int flat = tid + i * 256;
      int kvr = flat >> 5, dim = (flat & 31) * 4;
      f32x4 val = *(const f32x4*)(k + ((size_t)(kv0 + kvr) * NKV_ + kvh) * HD_ + dim);
      u16_t h0 = f2u(val[0]), h1 = f2u(val[1]), h2 = f2u(val[2]), h3 = f2u(val[3]);
      uint2v hv = {(unsigned)h0 | ((unsigned)h1 << 16), (unsigned)h2 | ((unsigned)h3 << 16)};
      uint2v lv = {(unsigned)f2u(val[0] - u2f(h0)) | ((unsigned)f2u(val[1] - u2f(h1)) << 16),
                   (unsigned)f2u(val[2] - u2f(h2)) | ((unsigned)f2u(val[3] - u2f(h3)) << 16)};
      int sH = ((dim >> 3)) ^ (kvr & 31);
      int sL = (16 + (dim >> 3)) ^ (kvr & 31);
      *(uint2v*)&Kl[kvr * 256 + sH * 8 + (dim & 7)] = hv;
      *(uint2v*)&Kl[kvr * 256 + sL * 8 + (dim & 7)] = lv;
    }
    // ---- stage V transposed: [dim][hl][kv], slot(16B)= (hl*8 + kv>>3) ^ ((dim^(dim>>4))&15) ----
#pragma unroll
    for (int i = 0; i < 8; ++i) {
      int flat = tid + i * 256;
      int kvr = flat >> 5, dim = (flat & 31) * 4;
      f32x4 val = *(const f32x4*)(v + ((size_t)(kv0 + kvr) * NKV_ + kvh) * HD_ + dim);
#pragma unroll
      for (int e = 0; e < 4; ++e) {
        int d = dim + e;
        u16_t hb = f2u(val[e]);
        u16_t lb = f2u(val[e] - u2f(hb));
        int fsw = (d ^ (d >> 4)) & 15;
        int sH = ((kvr >> 3)) ^ fsw;
        int sL = (8 + (kvr >> 3)) ^ fsw;
        Vl[d * 128 + sH * 8 + (kvr & 7)] = hb;
        Vl[d * 128 + sL * 8 + (kvr & 7)] = lb;
      }
    }
    __syncthreads();
    if (t > last_t) continue;

    // ---- QK^T (swapped: A=K, B=Q) -> accS[mf] = S^T, lane owns q-row c32 ----
    f32x16 accS[2] = {};
#pragma unroll
    for (int ks = 0; ks < 8; ++ks) {
      int db = g * 8 + ks * 16;
#pragma unroll
      for (int mf = 0; mf < 2; ++mf) {
        int kvr = c32 + mf * 32;
        bf16x8 ah = *(const bf16x8*)&Kl[kvr * 256 + (((db >> 3)) ^ c32) * 8];
        bf16x8 al = *(const bf16x8*)&Kl[kvr * 256 + ((16 + (db >> 3)) ^ c32) * 8];
        accS[mf] = __builtin_amdgcn_mfma_f32_32x32x16_bf16(ah, qh[ks], accS[mf], 0, 0, 0);
        accS[mf] = __builtin_amdgcn_mfma_f32_32x32x16_bf16(ah, ql[ks], accS[mf], 0, 0, 0);
        accS[mf] = __builtin_amdgcn_mfma_f32_32x32x16_bf16(al, qh[ks], accS[mf], 0, 0, 0);
      }
    }
    // ---- mask + online softmax (per lane = per q-row) ----
    float p[2][16];
    float tmax = -3.0e38f;
#pragma unroll
    for (int mf = 0; mf < 2; ++mf)
#pragma unroll
      for (int r = 0; r < 16; ++r) {
        int kvg = kv0 + mf * 32 + (r & 3) + 8 * (r >> 2) + 4 * g;
        float s = (kvg <= qrow) ? accS[mf][r] : -3.0e38f;
        p[mf][r] = s;
        tmax = fmaxf(tmax, s);
      }
    tmax = fmaxf(tmax, __shfl_xor(tmax, 32));
    float mn = fmaxf(m, tmax);
    float sc = __expf(m - mn);
    float ts = 0.f;
#pragma unroll
    for (int mf = 0; mf < 2; ++mf)
#pragma unroll
      for (int r = 0; r < 16; ++r) {
        float e = __expf(p[mf][r] - mn);
        p[mf][r] = e;
        ts += e;
      }
    ts += __shfl_xor(ts, 32);
    l = l * sc + ts;
    m = mn;
    // rescale accO rows
#pragma unroll
    for (int r = 0; r < 16; ++r) {
      int row16 = (r & 3) + 8 * (r >> 2) + 4 * g;
      float scr = __shfl(sc, row16);
#pragma unroll
      for (int nf = 0; nf < 4; ++nf) accO[nf][r] *= scr;
    }
    // ---- PV: A=P (packed in-register), B=V (from Vl) ----
#pragma unroll
    for (int ks = 0; ks < 4; ++ks) {
      int k1 = ks & 1, mf = ks >> 1;
      unsigned Lh[4], Ll[4];
#pragma unroll
      for (int i = 0; i < 4; ++i) {
        float a = p[mf][8 * k1 + 2 * i], b = p[mf][8 * k1 + 2 * i + 1];
        u16_t ha = f2u(a), hb = f2u(b);
        Lh[i] = (unsigned)ha | ((unsigned)hb << 16);
        Ll[i] = (unsigned)f2u(a - u2f(ha)) | ((unsigned)f2u(b - u2f(hb)) << 16);
      }
      unsigned Xh[4], Xl[4];
#pragma unroll
      for (int i = 0; i < 4; ++i) {
        Xh[i] = (unsigned)__shfl_xor((int)Lh[i], 32);
        Xl[i] = (unsigned)__shfl_xor((int)Ll[i], 32);
      }
      uint4v fh, fl;
      fh[0] = g ? Xh[2] : Lh[0]; fh[1] = g ? Xh[3] : Lh[1];
      fh[2] = g ? Lh[2] : Xh[0]; fh[3] = g ? Lh[3] : Xh[1];
      fl[0] = g ? Xl[2] : Ll[0]; fl[1] = g ? Xl[3] : Ll[1];
      fl[2] = g ? Ll[2] : Xl[0]; fl[3] = g ? Ll[3] : Xl[1];
      bf16x8 pH = __builtin_bit_cast(bf16x8, fh);
      bf16x8 pL = __builtin_bit_cast(bf16x8, fl);
      int kvb = g * 8 + ks * 16;
#pragma unroll
      for (int nf = 0; nf < 4; ++nf) {
        int d = c32 + nf * 32;
        int fsw = (d ^ (d >> 4)) & 15;
        bf16x8 vh = *(const bf16x8*)&Vl[d * 128 + (((kvb >> 3)) ^ fsw) * 8];
        bf16x8 vl = *(const bf16x8*)&Vl[d * 128 + ((8 + (kvb >> 3)) ^ fsw) * 8];
        accO[nf] = __builtin_amdgcn_mfma_f32_32x32x16_bf16(pH, vh, accO[nf], 0, 0, 0);
        accO[nf] = __builtin_amdgcn_mfma_f32_32x32x16_bf16(pH, vl, accO[nf], 0, 0, 0);
        accO[nf] = __builtin_amdgcn_mfma_f32_32x32x16_bf16(pL, vh, accO[nf], 0, 0, 0);
      }
    }
  }
  // ---- normalize + write ----
  float invl = 1.0f / l;
#pragma unroll
  for (int r = 0; r < 16; ++r) {
    int row16 = (r & 3) + 8 * (r >> 2) + 4 * g;
    float il = __shfl(invl, row16);
    int orow = q0 + w * 32 + row16;
#pragma unroll
    for (int nf = 0; nf < 4; ++nf)
      o[((size_t)orow * NH_ + h) * HD_ + nf * 32 + c32] = accO[nf][r] * il;
  }
}

// ---------------- router ----------------
__global__ __launch_bounds__(256) void router_k(const float* __restrict__ h2,
                                                const float* __restrict__ gw,
                                                int* __restrict__ counts, int* __restrict__ toklist,
                                                float* __restrict__ wlist, int* __restrict__ sel,
                                                int* __restrict__ pos) {
  int t = blockIdx.x, tid = threadIdx.x;
  int e = tid & 31, grp = tid >> 5;
  float acc = 0.f;
  for (int kk = grp; kk < H_; kk += 8)
    acc += h2[(size_t)t * H_ + kk] * gw[(size_t)kk * NE_ + e];
  __shared__ float part[8][32];
  part[grp][e] = acc;
  __syncthreads();
  if (tid == 0) {
    float lg[NE_];
    for (int ee = 0; ee < NE_; ++ee) {
      float s = 0.f;
      for (int g = 0; g < 8; ++g) s += part[g][ee];
      lg[ee] = s;
    }
    float m = lg[0];
    for (int ee = 1; ee < NE_; ++ee) m = fmaxf(m, lg[ee]);
    for (int ee = 0; ee < NE_; ++ee) lg[ee] = __expf(lg[ee] - m);
    bool used[NE_] = {};
    float rw[TOPK_]; int se[TOPK_]; float tot = 0.f;
    for (int kk = 0; kk < TOPK_; ++kk) {
      float best = -1.f; int bi = 0;
      for (int ee = 0; ee < NE_; ++ee)
        if (!used[ee] && lg[ee] > best) { best = lg[ee]; bi = ee; }
      used[bi] = true; se[kk] = bi; rw[kk] = best; tot += best;
    }
    float itot = 1.0f / tot;
    for (int kk = 0; kk < TOPK_; ++kk) {
      int ee = se[kk];
      int pp = atomicAdd(&counts[ee], 1);
      toklist[ee * S_ + pp] = t;
      wlist[ee * S_ + pp] = rw[kk] * itot;
      sel[t * TOPK_ + kk] = ee;
      pos[t * TOPK_ + kk] = pp;
    }
  }
}

__global__ void scan_k(const int* __restrict__ counts, int* __restrict__ offsets) {
  if (threadIdx.x == 0 && blockIdx.x == 0) {
    int o = 0;
    for (int e = 0; e < NE_; ++e) { offsets[e] = o; o += counts[e]; }
    offsets[NE_] = o;
  }
}

// ---------------- MoE up ----------------
template <bool BT>
__global__ __launch_bounds__(256, 1) void moe_up_k(const float* __restrict__ h2,
                                                   const float* __restrict__ wg,
                                                   const float* __restrict__ wu,
                                                   const bf16_t* __restrict__ wgT,
                                                   const bf16_t* __restrict__ wuT,
                                                   const int* __restrict__ toklist,
                                                   const int* __restrict__ counts,
                                                   const int* __restrict__ offsets,
                                                   bf16_t* __restrict__ act) {
  int eidx = blockIdx.z;
  int cnt = counts[eidx];
  int m0 = blockIdx.x * BM;
  if (m0 >= cnt) return;
  int n0 = blockIdx.y * BN;
  const int* toks = toklist + (size_t)eidx * S_;
  __shared__ __align__(16) bf16_t As[BM][LDK];
  __shared__ __align__(16) bf16_t Gs[BN][LDK];
  __shared__ __align__(16) bf16_t Us[BN][LDK];
  int tid = threadIdx.x, lane = tid & 63, wid = tid >> 6;
  int wr = (wid >> 1) * 64, wc = (wid & 1) * 64;
  int fr = lane & 15, kg = (lane >> 4) * 8;
  int sar = tid >> 1, sac = (tid & 1) * 16;
  int gi_l = min(m0 + sar, cnt - 1);
  const float* aptr = h2 + (size_t)toks[gi_l] * H_ + sac;
  const float* gptr = nullptr;
  const float* uptr = nullptr;
  const bf16_t* gtp = nullptr;
  const bf16_t* utp = nullptr;
  if constexpr (BT) {
    gtp = wgT + (size_t)eidx * H_ * I_ + (size_t)(n0 + sar) * H_ + sac;
    utp = wuT + (size_t)eidx * H_ * I_ + (size_t)(n0 + sar) * H_ + sac;
  } else {
    int sbr = tid >> 3, sbc = (tid & 7) * 16;
    gptr = wg + (size_t)eidx * H_ * I_ + (size_t)sbr * I_ + n0 + sbc;
    uptr = wu + (size_t)eidx * H_ * I_ + (size_t)sbr * I_ + n0 + sbc;
  }
  f32x4 accg[4][4] = {}, accu[4][4] = {};
  for (int k0 = 0; k0 < H_; k0 += BK) {
    {
      f32x4 t0 = *(const f32x4*)(aptr + k0);
      f32x4 t1 = *(const f32x4*)(aptr + k0 + 4);
      f32x4 t2 = *(const f32x4*)(aptr + k0 + 8);
      f32x4 t3 = *(const f32x4*)(aptr + k0 + 12);
      bf16x8 av0, av1;
#pragma unroll
      for (int i = 0; i < 4; ++i) {
        av0[i] = (__bf16)t0[i]; av0[i + 4] = (__bf16)t1[i];
        av1[i] = (__bf16)t2[i]; av1[i + 4] = (__bf16)t3[i];
      }
      *(bf16x8*)&As[sar][sac] = av0;
      *(bf16x8*)&As[sar][sac + 8] = av1;
    }
    if constexpr (BT) {
      bf16x8 g0 = *(const bf16x8*)(gtp + k0);
      bf16x8 g1 = *(const bf16x8*)(gtp + k0 + 8);
      *(bf16x8*)&Gs[sar][sac] = g0;
      *(bf16x8*)&Gs[sar][sac + 8] = g1;
      bf16x8 u0 = *(const bf16x8*)(utp + k0);
      bf16x8 u1 = *(const bf16x8*)(utp + k0 + 8);
      *(bf16x8*)&Us[sar][sac] = u0;
      *(bf16x8*)&Us[sar][sac + 8] = u1;
    } else {
      int sbr = tid >> 3, sbc = (tid & 7) * 16;
      {
        const float* bp = gptr + (size_t)k0 * I_;
        f32x4 b0 = *(const f32x4*)(bp);
        f32x4 b1 = *(const f32x4*)(bp + 4);
        f32x4 b2 = *(const f32x4*)(bp + 8);
        f32x4 b3 = *(const f32x4*)(bp + 12);
#pragma unroll
        for (int i = 0; i < 4; ++i) {
          Gs[sbc + i][sbr]      = (bf16_t)b0[i];
          Gs[sbc + 4 + i][sbr]  = (bf16_t)b1[i];
          Gs[sbc + 8 + i][sbr]  = (bf16_t)b2[i];
          Gs[sbc + 12 + i][sbr] = (bf16_t)b3[i];
        }
      }
      {
        const float* bp = uptr + (size_t)k0 * I_;
        f32x4 b0 = *(const f32x4*)(bp);
        f32x4 b1 = *(const f32x4*)(bp + 4);
        f32x4 b2 = *(const f32x4*)(bp + 8);
        f32x4 b3 = *(const f32x4*)(bp + 12);
#pragma unroll
        for (int i = 0; i < 4; ++i) {
          Us[sbc + i][sbr]      = (bf16_t)b0[i];
          Us[sbc + 4 + i][sbr]  = (bf16_t)b1[i];
          Us[sbc + 8 + i][sbr]  = (bf16_t)b2[i];
          Us[sbc + 12 + i][sbr] = (bf16_t)b3[i];
        }
      }
    }
    __syncthreads();
    bf16x8 af[4], gf[4], uf[4];
#pragma unroll
    for (int i = 0; i < 4; ++i) af[i] = *(const bf16x8*)&As[wr + i * 16 + fr][kg];
#pragma unroll
    for (int i = 0; i < 4; ++i) gf[i] = *(const bf16x8*)&Gs[wc + i * 16 + fr][kg];
#pragma unroll
    for (int i = 0; i < 4; ++i) uf[i] = *(const bf16x8*)&Us[wc + i * 16 + fr][kg];
#pragma unroll
    for (int mi = 0; mi < 4; ++mi)
#pragma unroll
      for (int ni = 0; ni < 4; ++ni) {
        accg[mi][ni] = __builtin_amdgcn_mfma_f32_16x16x32_bf16(af[mi], gf[ni], accg[mi][ni], 0, 0, 0);
        accu[mi][ni] = __builtin_amdgcn_mfma_f32_16x16x32_bf16(af[mi], uf[ni], accu[mi][ni], 0, 0, 0);
      }
    __syncthreads();
  }
  int rbase = (lane >> 4) * 4;
  int slotbase = offsets[eidx];
#pragma unroll
  for (int mi = 0; mi < 4; ++mi)
#pragma unroll
    for (int ni = 0; ni < 4; ++ni)
#pragma unroll
      for (int r = 0; r < 4; ++r) {
        int lr = wr + mi * 16 + rbase + r;
        int gi = m0 + lr;
        if (gi < cnt) {
          float g = accg[mi][ni][r], u = accu[mi][ni][r];
          float sig = 1.0f / (1.0f + __expf(-g));
          float a = g * sig * u;
          act[(size_t)(slotbase + gi) * I_ + n0 + wc + ni * 16 + fr] = (bf16_t)a;
        }
      }
}

// ---------------- combine ----------------
__global__ __launch_bounds__(256) void combine_k(const float* __restrict__ x1,
                                                 const bf16_t* __restrict__ pairout,
                                                 const int* __restrict__ sel,
                                                 const int* __restrict__ pos,
                                                 const int* __restrict__ offsets,
                                                 float* __restrict__ out) {
  int t = blockIdx.x, tid = threadIdx.x;
  int slots[TOPK_];
#pragma unroll
  for (int kk = 0; kk < TOPK_; ++kk)
    slots[kk] = offsets[sel[t * TOPK_ + kk]] + pos[t * TOPK_ + kk];
  int c = tid * 8;
  f32x4 s0 = *(const f32x4*)(x1 + (size_t)t * H_ + c);
  f32x4 s1 = *(const f32x4*)(x1 + (size_t)t * H_ + c + 4);
#pragma unroll
  for (int kk = 0; kk < TOPK_; ++kk) {
    bf16x8 pv = *(const bf16x8*)(pairout + (size_t)slots[kk] * H_ + c);
#pragma unroll
    for (int i = 0; i < 4; ++i) { s0[i] += (float)pv[i]; s1[i] += (float)pv[i + 4]; }
  }
  *(f32x4*)(out + (size_t)t * H_ + c) = s0;
  *(f32x4*)(out + (size_t)t * H_ + c + 4) = s1;
}

extern "C" void kernel_launch(void* const* d_in, const int* in_sizes, int n_in,
                              void* d_out, int out_size, void* d_ws, size_t ws_size,
                              hipStream_t stream) {
  const float* hidden = (const float*)d_in[0];
  const float* pe     = (const float*)d_in[1];
  const float* ln1    = (const float*)d_in[4];
  const float* ln2    = (const float*)d_in[5];
  const float* q_w    = (const float*)d_in[6];
  const float* k_w    = (const float*)d_in[7];
  const float* v_w    = (const float*)d_in[8];
  const float* o_w    = (const float*)d_in[9];
  const float* qn     = (const float*)d_in[10];
  const float* kn     = (const float*)d_in[11];
  const float* gate_w = (const float*)d_in[12];
  const float* wg     = (const float*)d_in[13];
  const float* wu     = (const float*)d_in[14];
  const float* wd     = (const float*)d_in[15];
  float* out = (float*)d_out;

  char* p = (char*)d_ws;
  auto alloc = [&](size_t bytes) {
    char* r = p;
    p += (bytes + 255) & ~(size_t)255;
    return r;
  };
  float*  h1      = (float*)alloc((size_t)S_ * H_ * 4);
  float*  qb      = (float*)alloc((size_t)S_ * NH_ * HD_ * 4);
  float*  kb      = (float*)alloc((size_t)S_ * NKV_ * HD_ * 4);
  float*  vb      = (float*)alloc((size_t)S_ * NKV_ * HD_ * 4);
  float*  ao      = (float*)alloc((size_t)S_ * NH_ * HD_ * 4);
  float*  x1      = (float*)alloc((size_t)S_ * H_ * 4);
  float*  h2      = (float*)alloc((size_t)S_ * H_ * 4);
  bf16_t* act     = (bf16_t*)alloc((size_t)S_ * TOPK_ * I_ * 2);
  bf16_t* po      = (bf16_t*)alloc((size_t)S_ * TOPK_ * H_ * 2);
  int*    counts  = (int*)alloc(NE_ * 4);
  int*    offs    = (int*)alloc((NE_ + 1) * 4);
  int*    toklist = (int*)alloc((size_t)NE_ * S_ * 4);
  float*  wlist   = (float*)alloc((size_t)NE_ * S_ * 4);
  int*    sel     = (int*)alloc((size_t)S_ * TOPK_ * 4);
  int*    pos     = (int*)alloc((size_t)S_ * TOPK_ * 4);
  bf16_t* qwT = (bf16_t*)alloc((size_t)H_ * (NH_ * HD_) * 2);
  bf16_t* kwT = (bf16_t*)alloc((size_t)H_ * (NKV_ * HD_) * 2);
  bf16_t* vwT = (bf16_t*)alloc((size_t)H_ * (NKV_ * HD_) * 2);
  bf16_t* owT = (bf16_t*)alloc((size_t)(NH_ * HD_) * H_ * 2);
  bf16_t* wgT = (bf16_t*)alloc((size_t)NE_ * H_ * I_ * 2);
  bf16_t* wuT = (bf16_t*)alloc((size_t)NE_ * H_ * I_ * 2);
  bf16_t* wdT = (bf16_t*)alloc((size_t)NE_ * I_ * H_ * 2);
  bool useBT = ((size_t)(p - (char*)d_ws) <= ws_size);

  hipMemsetAsync(counts, 0, NE_ * 4, stream);

  if (useBT) {
    transp_k<<<dim3((NH_ * HD_) / 32, H_ / 32, 1), 256, 0, stream>>>(q_w, qwT, H_, NH_ * HD_);
    transp_k<<<dim3((NKV_ * HD_) / 32, H_ / 32, 1), 256, 0, stream>>>(k_w, kwT, H_, NKV_ * HD_);
    transp_k<<<dim3((NKV_ * HD_) / 32, H_ / 32, 1), 256, 0, stream>>>(v_w, vwT, H_, NKV_ * HD_);
    transp_k<<<dim3(H_ / 32, (NH_ * HD_) / 32, 1), 256, 0, stream>>>(o_w, owT, NH_ * HD_, H_);
    transp_k<<<dim3(I_ / 32, H_ / 32, NE_), 256, 0, stream>>>(wg, wgT, H_, I_);
    transp_k<<<dim3(I_ / 32, H_ / 32, NE_), 256, 0, stream>>>(wu, wuT, H_, I_);
    transp_k<<<dim3(H_ / 32, I_ / 32, NE_), 256, 0, stream>>>(wd, wdT, I_, H_);
  }

  rmsnorm_k<<<S_, 256, 0, stream>>>(hidden, ln1, h1);
  if (useBT) {
    gemm_k<float, float, false, false, false, true>
        <<<dim3(S_ / BM, (NH_ * HD_) / BN), 256, 0, stream>>>(h1, nullptr, qwT, nullptr, qb, nullptr, nullptr, nullptr, S_, NH_ * HD_, H_);
    gemm_k<float, float, false, false, false, true>
        <<<dim3(S_ / BM, (NKV_ * HD_) / BN), 256, 0, stream>>>(h1, nullptr, kwT, nullptr, kb, nullptr, nullptr, nullptr, S_, NKV_ * HD_, H_);
    gemm_k<float, float, false, false, false, true>
        <<<dim3(S_ / BM, (NKV_ * HD_) / BN), 256, 0, stream>>>(h1, nullptr, vwT, nullptr, vb, nullptr, nullptr, nullptr, S_, NKV_ * HD_, H_);
  } else {
    gemm_k<float, float, false, false, false, false>
        <<<dim3(S_ / BM, (NH_ * HD_) / BN), 256, 0, stream>>>(h1, q_w, nullptr, nullptr, qb, nullptr, nullptr, nullptr, S_, NH_ * HD_, H_);
    gemm_k<float, float, false, false, false, false>
        <<<dim3(S_ / BM, (NKV_ * HD_) / BN), 256, 0, stream>>>(h1, k_w, nullptr, nullptr, kb, nullptr, nullptr, nullptr, S_, NKV_ * HD_, H_);
    gemm_k<float, float, false, false, false, false>
        <<<dim3(S_ / BM, (NKV_ * HD_) / BN), 256, 0, stream>>>(h1, v_w, nullptr, nullptr, vb, nullptr, nullptr, nullptr, S_, NKV_ * HD_, H_);
  }
  qknorm_rope_k<<<dim3(S_, NH_ + NKV_), 64, 0, stream>>>(qb, kb, qn, kn, pe);
  attn3_k<<<dim3(S_ / AQB, NH_), 256, 0, stream>>>(qb, kb, vb, ao);
  if (useBT) {
    gemm_k<float, float, false, true, false, true>
        <<<dim3(S_ / BM, H_ / BN), 256, 0, stream>>>(ao, nullptr, owT, hidden, x1, nullptr, nullptr, nullptr, S_, H_, NH_ * HD_);
  } else {
    gemm_k<float, float, false, true, false, false>
        <<<dim3(S_ / BM, H_ / BN), 256, 0, stream>>>(ao, o_w, nullptr, hidden, x1, nullptr, nullptr, nullptr, S_, H_, NH_ * HD_);
  }
  rmsnorm_k<<<S_, 256, 0, stream>>>(x1, ln2, h2);
  router_k<<<S_, 256, 0, stream>>>(h2, gate_w, counts, toklist, wlist, sel, pos);
  scan_k<<<1, 64, 0, stream>>>(counts, offs);
  if (useBT) {
    moe_up_k<true><<<dim3(S_ / BM, I_ / BN, NE_), 256, 0, stream>>>(h2, nullptr, nullptr, wgT, wuT, toklist, counts, offs, act);
    gemm_k<bf16_t, bf16_t, true, false, true, true>
        <<<dim3(S_ / BM, H_ / BN, NE_), 256, 0, stream>>>(act, nullptr, wdT, nullptr, po, wlist, counts, offs, 0, H_, I_);
  } else {
    moe_up_k<false><<<dim3(S_ / BM, I_ / BN, NE_), 256, 0, stream>>>(h2, wg, wu, nullptr, nullptr, toklist, counts, offs, act);
    gemm_k<bf16_t, bf16_t, true, false, true, false>
        <<<dim3(S_ / BM, H_ / BN, NE_), 256, 0, stream>>>(act, wd, nullptr, nullptr, po, wlist, counts, offs, 0, H_, I_);
  }
  combine_k<<<S_, 256, 0, stream>>>(x1, po, sel, pos, offs, out);
}

// Round 4
// 1129.238 us; speedup vs baseline: 3.2826x; 1.5527x over previous
//
#include <hip/hip_runtime.h>
#include <hip/hip_bf16.h>

#define S_ 1024
#define H_ 2048
#define NH_ 32
#define NKV_ 4
#define HD_ 128
#define NE_ 32
#define TOPK_ 8
#define I_ 768
#define EPS_ 1e-6f

typedef __bf16 bf16_t;
typedef __bf16 bf16x4v __attribute__((ext_vector_type(4)));
typedef __bf16 bf16x8 __attribute__((ext_vector_type(8)));
typedef float f32x4 __attribute__((ext_vector_type(4)));
typedef float f32x16 __attribute__((ext_vector_type(16)));
typedef unsigned short u16_t;
typedef unsigned int uint2v __attribute__((ext_vector_type(2)));
typedef unsigned int uint4v __attribute__((ext_vector_type(4)));

static __device__ __forceinline__ u16_t f2u(float x) {
  return __builtin_bit_cast(u16_t, (__bf16)x);
}
static __device__ __forceinline__ float u2f(u16_t u) {
  return (float)__builtin_bit_cast(__bf16, u);
}

// async global->LDS 16B per lane; dest wave-uniform base + lane*16
static __device__ __forceinline__ void gload16(const bf16_t* g, bf16_t* l) {
  __builtin_amdgcn_global_load_lds(
      (const __attribute__((address_space(1))) unsigned int*)g,
      (__attribute__((address_space(3))) unsigned int*)l, 16, 0, 0);
}

// ---------------- RMSNorm over H: fp32 (optional) + bf16 outputs ----------------
template <bool WF32>
__global__ __launch_bounds__(256) void rmsnorm2_k(const float* __restrict__ x,
                                                  const float* __restrict__ w,
                                                  float* __restrict__ outf,
                                                  bf16_t* __restrict__ outb) {
  int r = blockIdx.x, tid = threadIdx.x;
  const float* xr = x + (size_t)r * H_;
  f32x4 a = *(const f32x4*)(xr + tid * 8);
  f32x4 b = *(const f32x4*)(xr + tid * 8 + 4);
  float ss = 0.f;
#pragma unroll
  for (int i = 0; i < 4; ++i) ss += a[i] * a[i] + b[i] * b[i];
#pragma unroll
  for (int m = 1; m < 64; m <<= 1) ss += __shfl_xor(ss, m);
  __shared__ float wsum[4];
  if ((tid & 63) == 0) wsum[tid >> 6] = ss;
  __syncthreads();
  ss = wsum[0] + wsum[1] + wsum[2] + wsum[3];
  float inv = rsqrtf(ss * (1.0f / H_) + EPS_);
  f32x4 w0 = *(const f32x4*)(w + tid * 8);
  f32x4 w1 = *(const f32x4*)(w + tid * 8 + 4);
  f32x4 o0, o1;
#pragma unroll
  for (int i = 0; i < 4; ++i) { o0[i] = a[i] * inv * w0[i]; o1[i] = b[i] * inv * w1[i]; }
  if constexpr (WF32) {
    *(f32x4*)(outf + (size_t)r * H_ + tid * 8) = o0;
    *(f32x4*)(outf + (size_t)r * H_ + tid * 8 + 4) = o1;
  }
  bf16x8 ob;
#pragma unroll
  for (int i = 0; i < 4; ++i) { ob[i] = (__bf16)o0[i]; ob[i + 4] = (__bf16)o1[i]; }
  *(bf16x8*)(outb + (size_t)r * H_ + tid * 8) = ob;
}

// ---------------- weight transpose + bf16 convert: in[R][C] -> out[C][R], 64x64 tiles ----------------
__global__ __launch_bounds__(256) void transp2_k(const float* __restrict__ in,
                                                 bf16_t* __restrict__ out, int R, int C) {
  __shared__ float tile[64][65];
  size_t zin = (size_t)blockIdx.z * R * C;
  int tx = threadIdx.x & 15, ty = threadIdx.x >> 4;
  int r0 = blockIdx.y * 64, c0 = blockIdx.x * 64;
#pragma unroll
  for (int i = 0; i < 4; ++i) {
    f32x4 v = *(const f32x4*)(in + zin + (size_t)(r0 + ty + i * 16) * C + c0 + tx * 4);
    tile[ty + i * 16][tx * 4 + 0] = v[0];
    tile[ty + i * 16][tx * 4 + 1] = v[1];
    tile[ty + i * 16][tx * 4 + 2] = v[2];
    tile[ty + i * 16][tx * 4 + 3] = v[3];
  }
  __syncthreads();
#pragma unroll
  for (int i = 0; i < 4; ++i) {
    int oc = ty + i * 16;
    bf16x4v o;
#pragma unroll
    for (int j = 0; j < 4; ++j) o[j] = (bf16_t)tile[tx * 4 + j][oc];
    *(bf16x4v*)(out + zin + (size_t)(c0 + oc) * R + r0 + tx * 4) = o;
  }
}

// ---------------- unified 2-phase pipelined bf16 GEMM ----------------
// A[M][K] bf16 (opt. gathered rows), B pre-transposed [N][K] bf16 (opt. per-expert).
// DUAL: C_act = silu(A@B1) * (A@B2), bf16. Else C = A@B1 (*scale)(+resid), TC out.
// BMT x 64 tile, 8 waves, BK=32, double-buffered global_load_lds staging with
// XOR chunk swizzle (source and read use same involution: chunk ^ ((row>>1)&3)).
#define BK2 32
template <int BMT, typename TC, bool EXPERT, bool GATHER, bool RESID, bool SCALE, bool DUAL>
__global__ __launch_bounds__(512) void gemm2_k(
    const bf16_t* __restrict__ A, const bf16_t* __restrict__ B1g,
    const bf16_t* __restrict__ B2g, const float* __restrict__ resid,
    TC* __restrict__ C, bf16_t* __restrict__ act,
    const float* __restrict__ wlist, const int* __restrict__ counts,
    const int* __restrict__ offsets, const int* __restrict__ toklist,
    int M, int N, int K) {
  constexpr int MI = BMT / 64;      // A fragments per wave
  constexpr int ALW = BMT / 128;    // A wave-loads per k-step
  int e = 0, cnt = M, off = 0;
  const bf16_t* B1 = B1g;
  const bf16_t* B2 = B2g;
  const float* wl = nullptr;
  if constexpr (EXPERT) {
    e = blockIdx.z;
    cnt = counts[e];
    if ((int)(blockIdx.x * BMT) >= cnt) return;
    off = offsets[e];
    size_t bs = (size_t)K * N;
    B1 = B1g + (size_t)e * bs;
    if constexpr (DUAL) B2 = B2g + (size_t)e * bs;
    if constexpr (SCALE) wl = wlist + (size_t)e * S_;
  }
  constexpr int ASZ = 2 * BMT * BK2;
  constexpr int BSZ = 2 * 64 * BK2;
  __shared__ __align__(16) bf16_t smem[ASZ + BSZ + (DUAL ? BSZ : 0)];
  auto As = (bf16_t(*)[BMT][BK2])smem;
  auto B1s = (bf16_t(*)[64][BK2])(smem + ASZ);
  auto B2s = (bf16_t(*)[64][BK2])(smem + ASZ + BSZ);

  int tid = threadIdx.x, lane = tid & 63, w = tid >> 6;
  int m0 = blockIdx.x * BMT, n0 = blockIdx.y * 64;
  int srow = lane >> 2;
  int schunk = ((lane & 3) ^ ((lane >> 3) & 3)) * 8;  // element offset of 16B chunk

  const bf16_t* asrc[ALW];
#pragma unroll
  for (int i = 0; i < ALW; ++i) {
    int r = w * (16 * ALW) + i * 16 + srow;
    int gr = min(m0 + r, cnt - 1);
    size_t grow;
    if constexpr (GATHER) grow = (size_t)toklist[e * S_ + gr];
    else grow = (size_t)(off + gr);
    asrc[i] = A + grow * (size_t)K + schunk;
  }
  int bw = w & 3;
  bool isB2 = (w >= 4);
  const bf16_t* bsrc;
  {
    int r = bw * 16 + srow;
    const bf16_t* Bb = (DUAL && isB2) ? B2 : B1;
    bsrc = Bb + (size_t)(n0 + r) * K + schunk;
  }

  auto STAGE = [&](int t, int buf) {
    int ko = t * BK2;
#pragma unroll
    for (int i = 0; i < ALW; ++i)
      gload16(asrc[i] + ko, &As[buf][w * (16 * ALW) + i * 16][0]);
    if constexpr (DUAL) {
      gload16(bsrc + ko, isB2 ? &B2s[buf][bw * 16][0] : &B1s[buf][bw * 16][0]);
    } else {
      if (w < 4) gload16(bsrc + ko, &B1s[buf][bw * 16][0]);
    }
  };

  int fr = lane & 15, g = lane >> 4;
  int rk = (g ^ ((fr >> 1) & 3)) * 8;
  int wrv = (w >> 1) * (BMT / 4);
  int wcv = (w & 1) * 32;

  f32x4 acc1[MI][2] = {};
  f32x4 acc2[DUAL ? MI : 1][2] = {};

  int NT = K / BK2;
  STAGE(0, 0);
  __syncthreads();
  int cur = 0;
  for (int t = 0; t < NT; ++t) {
    if (t + 1 < NT) STAGE(t + 1, cur ^ 1);
    bf16x8 af[MI], b1f[2], b2f[2];
#pragma unroll
    for (int i = 0; i < MI; ++i) af[i] = *(const bf16x8*)&As[cur][wrv + i * 16 + fr][rk];
#pragma unroll
    for (int i = 0; i < 2; ++i) b1f[i] = *(const bf16x8*)&B1s[cur][wcv + i * 16 + fr][rk];
    if constexpr (DUAL) {
#pragma unroll
      for (int i = 0; i < 2; ++i) b2f[i] = *(const bf16x8*)&B2s[cur][wcv + i * 16 + fr][rk];
    }
#pragma unroll
    for (int mi = 0; mi < MI; ++mi)
#pragma unroll
      for (int ni = 0; ni < 2; ++ni) {
        acc1[mi][ni] = __builtin_amdgcn_mfma_f32_16x16x32_bf16(af[mi], b1f[ni], acc1[mi][ni], 0, 0, 0);
        if constexpr (DUAL)
          acc2[mi][ni] = __builtin_amdgcn_mfma_f32_16x16x32_bf16(af[mi], b2f[ni], acc2[mi][ni], 0, 0, 0);
      }
    __syncthreads();
    cur ^= 1;
  }

  int rbase = g * 4;
#pragma unroll
  for (int mi = 0; mi < MI; ++mi)
#pragma unroll
    for (int ni = 0; ni < 2; ++ni)
#pragma unroll
      for (int r = 0; r < 4; ++r) {
        int lr = wrv + mi * 16 + rbase + r;
        int gi = m0 + lr;
        if (EXPERT && gi >= cnt) continue;
        int gc = n0 + wcv + ni * 16 + fr;
        if constexpr (DUAL) {
          float gv = acc1[mi][ni][r], uv = acc2[mi][ni][r];
          float sig = 1.0f / (1.0f + __expf(-gv));
          act[(size_t)(off + gi) * N + gc] = (bf16_t)(gv * sig * uv);
        } else {
          float v = acc1[mi][ni][r];
          if constexpr (SCALE) v *= wl[gi];
          if constexpr (RESID) v += resid[(size_t)gi * N + gc];
          C[(size_t)(off + gi) * N + gc] = (TC)v;
        }
      }
}

// ---------------- Q/K head-RMSNorm + RoPE (in place) ----------------
__global__ __launch_bounds__(64) void qknorm_rope_k(float* __restrict__ qb, float* __restrict__ kb,
                                                    const float* __restrict__ qn,
                                                    const float* __restrict__ kn,
                                                    const float* __restrict__ pe) {
  int s = blockIdx.x, hh = blockIdx.y, lane = threadIdx.x;
  float* ptr;
  const float* w;
  if (hh < NH_) { ptr = qb + (size_t)s * NH_ * HD_ + hh * HD_; w = qn; }
  else          { ptr = kb + (size_t)s * NKV_ * HD_ + (hh - NH_) * HD_; w = kn; }
  float x0 = ptr[2 * lane], x1 = ptr[2 * lane + 1];
  float ss = x0 * x0 + x1 * x1;
#pragma unroll
  for (int m = 1; m < 64; m <<= 1) ss += __shfl_xor(ss, m);
  float inv = rsqrtf(ss * (1.0f / HD_) + EPS_);
  x0 = x0 * inv * w[2 * lane];
  x1 = x1 * inv * w[2 * lane + 1];
  float ang = pe[(size_t)s * (HD_ / 2) + lane];
  float sn, cs;
  sincosf(ang, &sn, &cs);
  ptr[2 * lane] = x0 * cs - x1 * sn;
  ptr[2 * lane + 1] = x0 * sn + x1 * cs;
}

// ---------------- attention v3: split-bf16 MFMA (fp32-accurate), causal GQA ----------------
#define AQB 128
#define AKV 64
__global__ __launch_bounds__(256, 2) void attn3_k(const float* __restrict__ q,
                                                  const float* __restrict__ k,
                                                  const float* __restrict__ v,
                                                  bf16_t* __restrict__ o) {
  int h = blockIdx.y, qblk = blockIdx.x;
  int q0 = qblk * AQB;
  int kvh = h >> 3;
  int tid = threadIdx.x, lane = tid & 63, w = tid >> 6;
  int g = lane >> 5, c32 = lane & 31;
  __shared__ __align__(16) u16_t Kl[AKV * 256];
  __shared__ __align__(16) u16_t Vl[128 * 128];

  int qrow = q0 + w * 32 + c32;
  const float scale = 0.08838834764831845f;

  bf16x8 qh[8], ql[8];
  {
    const float* qp = q + ((size_t)qrow * NH_ + h) * HD_;
#pragma unroll
    for (int ks = 0; ks < 8; ++ks) {
      int db = g * 8 + ks * 16;
      f32x4 a = *(const f32x4*)(qp + db);
      f32x4 b = *(const f32x4*)(qp + db + 4);
#pragma unroll
      for (int j = 0; j < 8; ++j) {
        float x = (j < 4 ? a[j & 3] : b[j & 3]) * scale;
        __bf16 hb = (__bf16)x;
        qh[ks][j] = hb;
        ql[ks][j] = (__bf16)(x - (float)hb);
      }
    }
  }

  f32x16 accO[4] = {};
  float m = -3.0e38f, l = 0.f;
  int last_t = (q0 + w * 32 + 31) >> 6;
  int NT = 2 * qblk + 2;

  for (int t = 0; t < NT; ++t) {
    int kv0 = t * AKV;
    __syncthreads();
#pragma unroll
    for (int i = 0; i < 8; ++i) {
      int flat = tid + i * 256;
      int kvr = flat >> 5, dim = (flat & 31) * 4;
      f32x4 val = *(const f32x4*)(k + ((size_t)(kv0 + kvr) * NKV_ + kvh) * HD_ + dim);
      u16_t h0 = f2u(val[0]), h1 = f2u(val[1]), h2 = f2u(val[2]), h3 = f2u(val[3]);
      uint2v hv = {(unsigned)h0 | ((unsigned)h1 << 16), (unsigned)h2 | ((unsigned)h3 << 16)};
      uint2v lv = {(unsigned)f2u(val[0] - u2f(h0)) | ((unsigned)f2u(val[1] - u2f(h1)) << 16),
                   (unsigned)f2u(val[2] - u2f(h2)) | ((unsigned)f2u(val[3] - u2f(h3)) << 16)};
      int sH = ((dim >> 3)) ^ (kvr & 31);
      int sL = (16 + (dim >> 3)) ^ (kvr & 31);
      *(uint2v*)&Kl[kvr * 256 + sH * 8 + (dim & 7)] = hv;
      *(uint2v*)&Kl[kvr * 256 + sL * 8 + (dim & 7)] = lv;
    }
#pragma unroll
    for (int i = 0; i < 8; ++i) {
      int flat = tid + i * 256;
      int kvr = flat >> 5, dim = (flat & 31) * 4;
      f32x4 val = *(const f32x4*)(v + ((size_t)(kv0 + kvr) * NKV_ + kvh) * HD_ + dim);
#pragma unroll
      for (int e = 0; e < 4; ++e) {
        int d = dim + e;
        u16_t hb = f2u(val[e]);
        u16_t lb = f2u(val[e] - u2f(hb));
        int fsw = (d ^ (d >> 4)) & 15;
        int sH = ((kvr >> 3)) ^ fsw;
        int sL = (8 + (kvr >> 3)) ^ fsw;
        Vl[d * 128 + sH * 8 + (kvr & 7)] = hb;
        Vl[d * 128 + sL * 8 + (kvr & 7)] = lb;
      }
    }
    __syncthreads();
    if (t > last_t) continue;

    f32x16 accS[2] = {};
#pragma unroll
    for (int ks = 0; ks < 8; ++ks) {
      int db = g * 8 + ks * 16;
#pragma unroll
      for (int mf = 0; mf < 2; ++mf) {
        int kvr = c32 + mf * 32;
        bf16x8 ah = *(const bf16x8*)&Kl[kvr * 256 + (((db >> 3)) ^ c32) * 8];
        bf16x8 al = *(const bf16x8*)&Kl[kvr * 256 + ((16 + (db >> 3)) ^ c32) * 8];
        accS[mf] = __builtin_amdgcn_mfma_f32_32x32x16_bf16(ah, qh[ks], accS[mf], 0, 0, 0);
        accS[mf] = __builtin_amdgcn_mfma_f32_32x32x16_bf16(ah, ql[ks], accS[mf], 0, 0, 0);
        accS[mf] = __builtin_amdgcn_mfma_f32_32x32x16_bf16(al, qh[ks], accS[mf], 0, 0, 0);
      }
    }
    float p[2][16];
    float tmax = -3.0e38f;
#pragma unroll
    for (int mf = 0; mf < 2; ++mf)
#pragma unroll
      for (int r = 0; r < 16; ++r) {
        int kvg = kv0 + mf * 32 + (r & 3) + 8 * (r >> 2) + 4 * g;
        float s = (kvg <= qrow) ? accS[mf][r] : -3.0e38f;
        p[mf][r] = s;
        tmax = fmaxf(tmax, s);
      }
    tmax = fmaxf(tmax, __shfl_xor(tmax, 32));
    float mn = fmaxf(m, tmax);
    float sc = __expf(m - mn);
    float ts = 0.f;
#pragma unroll
    for (int mf = 0; mf < 2; ++mf)
#pragma unroll
      for (int r = 0; r < 16; ++r) {
        float e = __expf(p[mf][r] - mn);
        p[mf][r] = e;
        ts += e;
      }
    ts += __shfl_xor(ts, 32);
    l = l * sc + ts;
    m = mn;
#pragma unroll
    for (int r = 0; r < 16; ++r) {
      int row16 = (r & 3) + 8 * (r >> 2) + 4 * g;
      float scr = __shfl(sc, row16);
#pragma unroll
      for (int nf = 0; nf < 4; ++nf) accO[nf][r] *= scr;
    }
#pragma unroll
    for (int ks = 0; ks < 4; ++ks) {
      int k1 = ks & 1, mf = ks >> 1;
      unsigned Lh[4], Ll[4];
#pragma unroll
      for (int i = 0; i < 4; ++i) {
        float a = p[mf][8 * k1 + 2 * i], b = p[mf][8 * k1 + 2 * i + 1];
        u16_t ha = f2u(a), hb = f2u(b);
        Lh[i] = (unsigned)ha | ((unsigned)hb << 16);
        Ll[i] = (unsigned)f2u(a - u2f(ha)) | ((unsigned)f2u(b - u2f(hb)) << 16);
      }
      unsigned Xh[4], Xl[4];
#pragma unroll
      for (int i = 0; i < 4; ++i) {
        Xh[i] = (unsigned)__shfl_xor((int)Lh[i], 32);
        Xl[i] = (unsigned)__shfl_xor((int)Ll[i], 32);
      }
      uint4v fh, fl;
      fh[0] = g ? Xh[2] : Lh[0]; fh[1] = g ? Xh[3] : Lh[1];
      fh[2] = g ? Lh[2] : Xh[0]; fh[3] = g ? Lh[3] : Xh[1];
      fl[0] = g ? Xl[2] : Ll[0]; fl[1] = g ? Xl[3] : Ll[1];
      fl[2] = g ? Ll[2] : Xl[0]; fl[3] = g ? Ll[3] : Xl[1];
      bf16x8 pH = __builtin_bit_cast(bf16x8, fh);
      bf16x8 pL = __builtin_bit_cast(bf16x8, fl);
      int kvb = g * 8 + ks * 16;
#pragma unroll
      for (int nf = 0; nf < 4; ++nf) {
        int d = c32 + nf * 32;
        int fsw = (d ^ (d >> 4)) & 15;
        bf16x8 vh = *(const bf16x8*)&Vl[d * 128 + (((kvb >> 3)) ^ fsw) * 8];
        bf16x8 vl = *(const bf16x8*)&Vl[d * 128 + ((8 + (kvb >> 3)) ^ fsw) * 8];
        accO[nf] = __builtin_amdgcn_mfma_f32_32x32x16_bf16(pH, vh, accO[nf], 0, 0, 0);
        accO[nf] = __builtin_amdgcn_mfma_f32_32x32x16_bf16(pH, vl, accO[nf], 0, 0, 0);
        accO[nf] = __builtin_amdgcn_mfma_f32_32x32x16_bf16(pL, vh, accO[nf], 0, 0, 0);
      }
    }
  }
  float invl = 1.0f / l;
#pragma unroll
  for (int r = 0; r < 16; ++r) {
    int row16 = (r & 3) + 8 * (r >> 2) + 4 * g;
    float il = __shfl(invl, row16);
    int orow = q0 + w * 32 + row16;
#pragma unroll
    for (int nf = 0; nf < 4; ++nf)
      o[((size_t)orow * NH_ + h) * HD_ + nf * 32 + c32] = (bf16_t)(accO[nf][r] * il);
  }
}

// ---------------- router ----------------
__global__ __launch_bounds__(256) void router_k(const float* __restrict__ h2,
                                                const float* __restrict__ gw,
                                                int* __restrict__ counts, int* __restrict__ toklist,
                                                float* __restrict__ wlist, int* __restrict__ sel,
                                                int* __restrict__ pos) {
  int t = blockIdx.x, tid = threadIdx.x;
  int e = tid & 31, grp = tid >> 5;
  float acc = 0.f;
  for (int kk = grp; kk < H_; kk += 8)
    acc += h2[(size_t)t * H_ + kk] * gw[(size_t)kk * NE_ + e];
  __shared__ float part[8][32];
  part[grp][e] = acc;
  __syncthreads();
  if (tid == 0) {
    float lg[NE_];
    for (int ee = 0; ee < NE_; ++ee) {
      float s = 0.f;
      for (int g = 0; g < 8; ++g) s += part[g][ee];
      lg[ee] = s;
    }
    float m = lg[0];
    for (int ee = 1; ee < NE_; ++ee) m = fmaxf(m, lg[ee]);
    for (int ee = 0; ee < NE_; ++ee) lg[ee] = __expf(lg[ee] - m);
    bool used[NE_] = {};
    float rw[TOPK_]; int se[TOPK_]; float tot = 0.f;
    for (int kk = 0; kk < TOPK_; ++kk) {
      float best = -1.f; int bi = 0;
      for (int ee = 0; ee < NE_; ++ee)
        if (!used[ee] && lg[ee] > best) { best = lg[ee]; bi = ee; }
      used[bi] = true; se[kk] = bi; rw[kk] = best; tot += best;
    }
    float itot = 1.0f / tot;
    for (int kk = 0; kk < TOPK_; ++kk) {
      int ee = se[kk];
      int pp = atomicAdd(&counts[ee], 1);
      toklist[ee * S_ + pp] = t;
      wlist[ee * S_ + pp] = rw[kk] * itot;
      sel[t * TOPK_ + kk] = ee;
      pos[t * TOPK_ + kk] = pp;
    }
  }
}

__global__ void scan_k(const int* __restrict__ counts, int* __restrict__ offsets) {
  if (threadIdx.x == 0 && blockIdx.x == 0) {
    int o = 0;
    for (int e = 0; e < NE_; ++e) { offsets[e] = o; o += counts[e]; }
    offsets[NE_] = o;
  }
}

// ---------------- combine ----------------
__global__ __launch_bounds__(256) void combine_k(const float* __restrict__ x1,
                                                 const bf16_t* __restrict__ pairout,
                                                 const int* __restrict__ sel,
                                                 const int* __restrict__ pos,
                                                 const int* __restrict__ offsets,
                                                 float* __restrict__ out) {
  int t = blockIdx.x, tid = threadIdx.x;
  int slots[TOPK_];
#pragma unroll
  for (int kk = 0; kk < TOPK_; ++kk)
    slots[kk] = offsets[sel[t * TOPK_ + kk]] + pos[t * TOPK_ + kk];
  int c = tid * 8;
  f32x4 s0 = *(const f32x4*)(x1 + (size_t)t * H_ + c);
  f32x4 s1 = *(const f32x4*)(x1 + (size_t)t * H_ + c + 4);
#pragma unroll
  for (int kk = 0; kk < TOPK_; ++kk) {
    bf16x8 pv = *(const bf16x8*)(pairout + (size_t)slots[kk] * H_ + c);
#pragma unroll
    for (int i = 0; i < 4; ++i) { s0[i] += (float)pv[i]; s1[i] += (float)pv[i + 4]; }
  }
  *(f32x4*)(out + (size_t)t * H_ + c) = s0;
  *(f32x4*)(out + (size_t)t * H_ + c + 4) = s1;
}

extern "C" void kernel_launch(void* const* d_in, const int* in_sizes, int n_in,
                              void* d_out, int out_size, void* d_ws, size_t ws_size,
                              hipStream_t stream) {
  const float* hidden = (const float*)d_in[0];
  const float* pe     = (const float*)d_in[1];
  const float* ln1    = (const float*)d_in[4];
  const float* ln2    = (const float*)d_in[5];
  const float* q_w    = (const float*)d_in[6];
  const float* k_w    = (const float*)d_in[7];
  const float* v_w    = (const float*)d_in[8];
  const float* o_w    = (const float*)d_in[9];
  const float* qn     = (const float*)d_in[10];
  const float* kn     = (const float*)d_in[11];
  const float* gate_w = (const float*)d_in[12];
  const float* wg     = (const float*)d_in[13];
  const float* wu     = (const float*)d_in[14];
  const float* wd     = (const float*)d_in[15];
  float* out = (float*)d_out;

  char* p = (char*)d_ws;
  auto alloc = [&](size_t bytes) {
    char* r = p;
    p += (bytes + 255) & ~(size_t)255;
    return r;
  };
  bf16_t* h1b     = (bf16_t*)alloc((size_t)S_ * H_ * 2);
  float*  qb      = (float*)alloc((size_t)S_ * NH_ * HD_ * 4);
  float*  kb      = (float*)alloc((size_t)S_ * NKV_ * HD_ * 4);
  float*  vb      = (float*)alloc((size_t)S_ * NKV_ * HD_ * 4);
  bf16_t* aob     = (bf16_t*)alloc((size_t)S_ * NH_ * HD_ * 2);
  float*  x1      = (float*)alloc((size_t)S_ * H_ * 4);
  float*  h2      = (float*)alloc((size_t)S_ * H_ * 4);
  bf16_t* h2b     = (bf16_t*)alloc((size_t)S_ * H_ * 2);
  bf16_t* act     = (bf16_t*)alloc((size_t)S_ * TOPK_ * I_ * 2);
  bf16_t* po      = (bf16_t*)alloc((size_t)S_ * TOPK_ * H_ * 2);
  int*    counts  = (int*)alloc(NE_ * 4);
  int*    offs    = (int*)alloc((NE_ + 1) * 4);
  int*    toklist = (int*)alloc((size_t)NE_ * S_ * 4);
  float*  wlist   = (float*)alloc((size_t)NE_ * S_ * 4);
  int*    sel     = (int*)alloc((size_t)S_ * TOPK_ * 4);
  int*    pos     = (int*)alloc((size_t)S_ * TOPK_ * 4);
  bf16_t* qwT = (bf16_t*)alloc((size_t)H_ * (NH_ * HD_) * 2);
  bf16_t* kwT = (bf16_t*)alloc((size_t)H_ * (NKV_ * HD_) * 2);
  bf16_t* vwT = (bf16_t*)alloc((size_t)H_ * (NKV_ * HD_) * 2);
  bf16_t* owT = (bf16_t*)alloc((size_t)(NH_ * HD_) * H_ * 2);
  bf16_t* wgT = (bf16_t*)alloc((size_t)NE_ * H_ * I_ * 2);
  bf16_t* wuT = (bf16_t*)alloc((size_t)NE_ * H_ * I_ * 2);
  bf16_t* wdT = (bf16_t*)alloc((size_t)NE_ * I_ * H_ * 2);

  hipMemsetAsync(counts, 0, NE_ * 4, stream);

  transp2_k<<<dim3((NH_ * HD_) / 64, H_ / 64, 1), 256, 0, stream>>>(q_w, qwT, H_, NH_ * HD_);
  transp2_k<<<dim3((NKV_ * HD_) / 64, H_ / 64, 1), 256, 0, stream>>>(k_w, kwT, H_, NKV_ * HD_);
  transp2_k<<<dim3((NKV_ * HD_) / 64, H_ / 64, 1), 256, 0, stream>>>(v_w, vwT, H_, NKV_ * HD_);
  transp2_k<<<dim3(H_ / 64, (NH_ * HD_) / 64, 1), 256, 0, stream>>>(o_w, owT, NH_ * HD_, H_);
  transp2_k<<<dim3(I_ / 64, H_ / 64, NE_), 256, 0, stream>>>(wg, wgT, H_, I_);
  transp2_k<<<dim3(I_ / 64, H_ / 64, NE_), 256, 0, stream>>>(wu, wuT, H_, I_);
  transp2_k<<<dim3(H_ / 64, I_ / 64, NE_), 256, 0, stream>>>(wd, wdT, I_, H_);

  rmsnorm2_k<false><<<S_, 256, 0, stream>>>(hidden, ln1, nullptr, h1b);
  // QKV projections
  gemm2_k<128, float, false, false, false, false, false>
      <<<dim3(S_ / 128, (NH_ * HD_) / 64), 512, 0, stream>>>(
          h1b, qwT, nullptr, nullptr, qb, nullptr, nullptr, nullptr, nullptr, nullptr,
          S_, NH_ * HD_, H_);
  gemm2_k<128, float, false, false, false, false, false>
      <<<dim3(S_ / 128, (NKV_ * HD_) / 64), 512, 0, stream>>>(
          h1b, kwT, nullptr, nullptr, kb, nullptr, nullptr, nullptr, nullptr, nullptr,
          S_, NKV_ * HD_, H_);
  gemm2_k<128, float, false, false, false, false, false>
      <<<dim3(S_ / 128, (NKV_ * HD_) / 64), 512, 0, stream>>>(
          h1b, vwT, nullptr, nullptr, vb, nullptr, nullptr, nullptr, nullptr, nullptr,
          S_, NKV_ * HD_, H_);
  qknorm_rope_k<<<dim3(S_, NH_ + NKV_), 64, 0, stream>>>(qb, kb, qn, kn, pe);
  attn3_k<<<dim3(S_ / AQB, NH_), 256, 0, stream>>>(qb, kb, vb, aob);
  // O projection + residual
  gemm2_k<128, float, false, false, true, false, false>
      <<<dim3(S_ / 128, H_ / 64), 512, 0, stream>>>(
          aob, owT, nullptr, hidden, x1, nullptr, nullptr, nullptr, nullptr, nullptr,
          S_, H_, NH_ * HD_);
  rmsnorm2_k<true><<<S_, 256, 0, stream>>>(x1, ln2, h2, h2b);
  router_k<<<S_, 256, 0, stream>>>(h2, gate_w, counts, toklist, wlist, sel, pos);
  scan_k<<<1, 64, 0, stream>>>(counts, offs);
  // MoE up (fused gate+up+silu)
  gemm2_k<256, float, true, true, false, false, true>
      <<<dim3(S_ / 256, I_ / 64, NE_), 512, 0, stream>>>(
          h2b, wgT, wuT, nullptr, nullptr, act, nullptr, counts, offs, toklist,
          S_, I_, H_);
  // MoE down (+ routing weight scale)
  gemm2_k<256, bf16_t, true, false, false, true, false>
      <<<dim3(S_ / 256, H_ / 64, NE_), 512, 0, stream>>>(
          act, wdT, nullptr, nullptr, po, nullptr, wlist, counts, offs, nullptr,
          S_, H_, I_);
  combine_k<<<S_, 256, 0, stream>>>(x1, po, sel, pos, offs, out);
}